// Round 11
// baseline (837.751 us; speedup 1.0000x reference)
//
#include <hip/hip_runtime.h>
#include <hip/hip_bf16.h>
#include <hip/hip_fp16.h>

// Problem constants
#define NB 64
#define NT 256
#define TC 16
#define NL 25
#define NWORDS 16384   // NB*NT
#define DWd 150        // word-LSTM input dim
#define WEd 100
#define WPB 5          // words per k_char block

typedef _Float16 f16x8 __attribute__((ext_vector_type(8)));
typedef _Float16 f16x4 __attribute__((ext_vector_type(4)));
typedef float    f32x4 __attribute__((ext_vector_type(4)));

__device__ __forceinline__ float sigf(float x){ return __fdividef(1.f, 1.f + __expf(-x)); }
__device__ __forceinline__ float tanhf_(float x){
    float ax = fabsf(x);
    float e = __expf(-2.f*ax);                 // e in (0,1], overflow-safe
    float r = (1.f - e) * __fdividef(1.f, 1.f + e);
    return copysignf(r, x);
}

// ---------------- Kernel 0: gxc[(c,d)][col] = cb_d[col] + sum_k char_emb[c][k]*cWih_d[k*100+col]
__global__ void k_gxc(const float* __restrict__ char_emb,
                      const float* __restrict__ cWih_f, const float* __restrict__ cb_f,
                      const float* __restrict__ cWih_b, const float* __restrict__ cb_b,
                      float* __restrict__ gxc){
  int i = blockIdx.x*blockDim.x + threadIdx.x;
  if (i >= 128*2*100) return;
  int col = i % 100; int d = (i/100) & 1; int c = i/200;
  const float* Wih = d ? cWih_b : cWih_f;
  const float* bb  = d ? cb_b  : cb_f;
  float acc = bb[col];
  #pragma unroll
  for (int k=0;k<25;k++) acc += char_emb[c*25+k]*Wih[k*100+col];
  gxc[i] = acc;
}

// ---------------- Kernel 0b: WhP[d][k(128)][colp(448)] f16, gate-padded (112 cols/gate), zero pads
__global__ void k_prep(const float* __restrict__ whf, const float* __restrict__ whb,
                       _Float16* __restrict__ WhP){
  int i = blockIdx.x*blockDim.x + threadIdx.x;
  if (i >= 2*128*448) return;
  int colp = i % 448; int k = (i/448) % 128; int d = i/(448*128);
  int g = colp/112, uu = colp%112;
  const float* W = d ? whb : whf;
  WhP[i] = (k < 100 && uu < 100) ? (_Float16)W[k*400 + g*100 + uu] : (_Float16)0.f;
}

// ---------------- Kernel 1: char BiLSTM, thread = (word_in_block, gate_col).
__global__ __launch_bounds__(512) void k_char(const int* __restrict__ char_tensor,
   const int* __restrict__ char_lengths,
   const float* __restrict__ cWhh_f, const float* __restrict__ cWhh_b,
   const float* __restrict__ gxc, float* __restrict__ cf){
  __shared__ float h_lds[WPB][28];
  __shared__ float act[WPB][100];
  __shared__ int   chars[WPB][TC];
  __shared__ int   lens[WPB];
  int tid = threadIdx.x;
  int d  = blockIdx.x & 1;
  int wb = blockIdx.x >> 1;
  int w0 = wb*WPB;
  if (tid < WPB*TC){
    int ww = w0 + tid/TC;
    int cw = ww < NWORDS ? ww : NWORDS-1;
    chars[tid/TC][tid%TC] = char_tensor[cw*TC + (tid%TC)];
  }
  if (tid < WPB){
    int ww = w0 + tid;
    lens[tid] = char_lengths[ww < NWORDS ? ww : NWORDS-1];
  }
  int wsub = tid/100;
  int j    = tid - wsub*100;
  bool gate_thr = tid < WPB*100;
  const float* Wh = d ? cWhh_b : cWhh_f;
  float wcol[25];
  if (gate_thr){
    #pragma unroll
    for (int k=0;k<25;k++) wcol[k] = Wh[k*100 + j];
  }
  if (gate_thr && j < 28) h_lds[wsub][j] = 0.f;
  float c_reg = 0.f, h_last = 0.f;
  __syncthreads();
  int len = gate_thr ? lens[wsub] : 1;
  bool isg = (j >= 50) && (j < 75);
  float g_all[TC];
  if (gate_thr){
    #pragma unroll
    for (int t=0;t<TC;t++){
      int ci = d ? (len-1-t) : t;
      if (ci < 0 || ci >= TC) ci = 0;
      int cidx = chars[wsub][ci];
      g_all[t] = gxc[(size_t)(cidx*2+d)*100 + j];
    }
  }
  for (int t=0;t<TC;t++){
    if (gate_thr){
      float a = g_all[t];
      const float4* h4 = (const float4*)h_lds[wsub];
      #pragma unroll
      for (int kq=0;kq<6;kq++){
        float4 hq = h4[kq];
        a += hq.x*wcol[4*kq] + hq.y*wcol[4*kq+1] + hq.z*wcol[4*kq+2] + hq.w*wcol[4*kq+3];
      }
      a += h_lds[wsub][24]*wcol[24];
      act[wsub][j] = isg ? tanhf_(a) : sigf(a);
    }
    __syncthreads();
    if (gate_thr && j < 25 && t < len){
      float si = act[wsub][j], sf = act[wsub][25+j], sg = act[wsub][50+j], so = act[wsub][75+j];
      c_reg = sf*c_reg + si*sg;
      float hv = so*tanhf_(c_reg);
      h_lds[wsub][j] = hv;
      h_last = hv;
    }
    __syncthreads();
  }
  if (gate_thr && j < 25){
    int w = w0 + wsub;
    if (w < NWORDS) cf[(size_t)w*56 + d*28 + j] = h_last;
  }
}

// ---------------- Kernel 2: x[p][150] = word_emb[tok[p]] ++ cf[recover[p]] (cf stride 56)
__global__ void k_buildx(const int* __restrict__ tok, const int* __restrict__ recover,
                         const float* __restrict__ word_emb, const float* __restrict__ cf,
                         float* __restrict__ x){
  long i = (long)blockIdx.x*blockDim.x + threadIdx.x;
  if (i >= (long)NWORDS*DWd) return;
  int p = (int)(i/DWd); int e = (int)(i - (long)p*DWd);
  float v;
  if (e < WEd) v = word_emb[(long)tok[p]*WEd + e];
  else {
    int cidx = e - WEd;
    int dd = cidx / 25; int uu = cidx - dd*25;
    v = cf[(size_t)recover[p]*56 + dd*28 + uu];
  }
  x[i] = v;
}

// ---------------- Kernel 3: gx16[d][p][400] (f16) = wb_d + x[p] @ wWih_d
__global__ __launch_bounds__(256) void k_wih(const float* __restrict__ x,
    const float* __restrict__ Wf, const float* __restrict__ bf,
    const float* __restrict__ Wb, const float* __restrict__ bbias,
    _Float16* __restrict__ gx16){
  __shared__ float As[150][36];
  int tid = threadIdx.x;
  int m0 = (blockIdx.x>>2)*32;
  int nt = blockIdx.x & 3;
  int n0 = nt*256;
  for (int i=tid; i<32*150; i+=256){
    int r = i/150; int k = i - r*150;
    As[k][r] = x[(long)(m0+r)*150 + k];
  }
  __syncthreads();
  int tn = tid & 31; int tm = tid >> 5;
  int j0 = n0 + tn*8;
  bool colok = j0 < 800;
  int d = (j0 >= 400) ? 1 : 0;
  const float* W = d ? Wb : Wf;
  int jc = j0 - d*400;
  float acc[4][8];
  #pragma unroll
  for (int mi=0;mi<4;mi++)
    #pragma unroll
    for (int ni=0;ni<8;ni++) acc[mi][ni]=0.f;
  if (colok){
    for (int k=0;k<150;k++){
      float4 b0 = *(const float4*)&W[k*400 + jc];
      float4 b1 = *(const float4*)&W[k*400 + jc + 4];
      float4 a4 = *(const float4*)&As[k][tm*4];
      float av[4] = {a4.x,a4.y,a4.z,a4.w};
      float bv[8] = {b0.x,b0.y,b0.z,b0.w,b1.x,b1.y,b1.z,b1.w};
      #pragma unroll
      for (int mi=0;mi<4;mi++)
        #pragma unroll
        for (int ni=0;ni<8;ni++) acc[mi][ni] += av[mi]*bv[ni];
    }
    const float* bptr = d ? bbias : bf;
    float bias[8];
    #pragma unroll
    for (int ni=0;ni<8;ni++) bias[ni] = bptr[jc+ni];
    #pragma unroll
    for (int mi=0;mi<4;mi++){
      int p = m0 + tm*4 + mi;
      f16x8 h8;
      #pragma unroll
      for (int ni=0;ni<8;ni++) h8[ni] = (_Float16)(acc[mi][ni] + bias[ni]);
      *(f16x8*)&gx16[((long)d*NWORDS + p)*400 + jc] = h8;
    }
  }
}

// ---------------- Kernel 3b: permute gx16 -> gxP[bid=(d*4+grp)][step][colp(448)][seq(16)] f16
// step order pre-reversed for d=1; pad cols (u>=100) written zero.
__global__ __launch_bounds__(448) void k_perm(const _Float16* __restrict__ gx16,
                                              _Float16* __restrict__ gxP){
  int bid = blockIdx.x;            // (d*4+grp)*256 + step
  int step = bid & 255; int dg = bid >> 8; int d = dg >> 2; int grp = dg & 3;
  int t = d ? (255 - step) : step;
  int colp = threadIdx.x;          // 0..447
  int g = colp / 112, uu = colp % 112;
  f16x8 v0, v1;
  if (uu < 100){
    int col = g*100 + uu;
    const _Float16* src = gx16 + ((size_t)d*NWORDS + (size_t)grp*16*256 + t)*400 + col;
    #pragma unroll
    for (int q=0;q<8;q++) v0[q] = src[(size_t)q*256*400];
    #pragma unroll
    for (int q=0;q<8;q++) v1[q] = src[(size_t)(q+8)*256*400];
  } else {
    #pragma unroll
    for (int q=0;q<8;q++){ v0[q] = (_Float16)0.f; v1[q] = (_Float16)0.f; }
  }
  _Float16* dst = gxP + ((size_t)bid*448 + colp)*16;
  *(f16x8*)dst = v0;
  *(f16x8*)(dst+8) = v1;
}

// ---------------- Kernel 4: word LSTM recurrence v10 — MFMA-batched.
// block = (dir, group of 16 seqs): 8 blocks x 448 thr (7 waves). Per step:
// G(16x448) = H(16x128,f16) @ WhP(128x448,f16) via 16x16x32 MFMA, gx as C-init.
// Gate padded to 112 cols; wave w takes tile w of EVERY gate -> each lane's acc
// regs hold i,f,g,o of the same (seq,unit): activations+c fully in-lane, c in
// regs. h -> LDS f16 (double-buffered parity). ONE raw s_barrier/step preceded
// by lgkmcnt(0) ONLY (T4): gxP prefetch loads stay in flight across barriers.
__global__ __launch_bounds__(448, 1) void k_wlstm(const _Float16* __restrict__ gxP,
     const _Float16* __restrict__ WhP, float* __restrict__ hseq){
  __shared__ _Float16 H[2][16][136];
  int tid = threadIdx.x;
  int lane = tid & 63, w = tid >> 6;          // w = 0..6
  int bid = blockIdx.x;                       // d*4 + grp
  int d = bid >> 2; int grp = bid & 3;
  int li = lane & 15, lk = lane >> 4;         // li: M/N idx, lk: k-group
  int u = 16*w + li;                          // unit col within gate, 0..111
  // B-fragments (gate-stationary weights; MFMA reads them from VGPR/AGPR natively)
  f16x8 Bf[4][4];
  {
    const _Float16* Wd = WhP + (size_t)d*128*448;
    #pragma unroll
    for (int g=0; g<4; ++g){
      int colp = 112*g + u;
      #pragma unroll
      for (int kk=0; kk<4; ++kk){
        f16x8 b;
        #pragma unroll
        for (int j=0;j<8;j++) b[j] = Wd[(size_t)(kk*32 + lk*8 + j)*448 + colp];
        Bf[g][kk] = b;
      }
    }
  }
  for (int i=tid; i<2*16*136; i+=448) ((_Float16*)H)[i] = (_Float16)0.f;
  float c0=0.f, c1=0.f, c2=0.f, c3=0.f;
  const _Float16* gxb = gxP + (size_t)bid*256*448*16;
  long hb0 = ((long)d*NWORDS + (long)grp*16*256)*100;
  f16x4 pA[4], pB[4];
#define PREF(P, ST) { const _Float16* _r = gxb + (size_t)(ST)*448*16 + (size_t)lk*4; \
    _Pragma("unroll") for (int g=0; g<4; ++g) \
      P[g] = *(const f16x4*)(_r + (size_t)(112*g + u)*16); }
  PREF(pA, 0)
  PREF(pB, 1)
  __syncthreads();

#define MF(A,B,C) __builtin_amdgcn_mfma_f32_16x16x32_f16(A, B, C, 0, 0, 0)
#define CVT4(P) (f32x4){(float)(P)[0], (float)(P)[1], (float)(P)[2], (float)(P)[3]}
#define STEPB(P, T) { \
    const int par = (T) & 1; \
    f16x8 a0 = *(const f16x8*)&H[par][li][ 0 + lk*8]; \
    f16x8 a1 = *(const f16x8*)&H[par][li][32 + lk*8]; \
    f16x8 a2 = *(const f16x8*)&H[par][li][64 + lk*8]; \
    f16x8 a3 = *(const f16x8*)&H[par][li][96 + lk*8]; \
    f32x4 ai = CVT4(P[0]), af = CVT4(P[1]), ag = CVT4(P[2]), ao = CVT4(P[3]); \
    ai = MF(a0, Bf[0][0], ai); ai = MF(a1, Bf[0][1], ai); ai = MF(a2, Bf[0][2], ai); ai = MF(a3, Bf[0][3], ai); \
    af = MF(a0, Bf[1][0], af); af = MF(a1, Bf[1][1], af); af = MF(a2, Bf[1][2], af); af = MF(a3, Bf[1][3], af); \
    ag = MF(a0, Bf[2][0], ag); ag = MF(a1, Bf[2][1], ag); ag = MF(a2, Bf[2][2], ag); ag = MF(a3, Bf[2][3], ag); \
    ao = MF(a0, Bf[3][0], ao); ao = MF(a1, Bf[3][1], ao); ao = MF(a2, Bf[3][2], ao); ao = MF(a3, Bf[3][3], ao); \
    if ((T)+2 < 256) PREF(P, (T)+2) \
    int ttc = d ? (255-(T)) : (T); \
    float hv0, hv1, hv2, hv3; \
    c0 = sigf(af[0])*c0 + sigf(ai[0])*tanhf_(ag[0]); hv0 = sigf(ao[0])*tanhf_(c0); \
    c1 = sigf(af[1])*c1 + sigf(ai[1])*tanhf_(ag[1]); hv1 = sigf(ao[1])*tanhf_(c1); \
    c2 = sigf(af[2])*c2 + sigf(ai[2])*tanhf_(ag[2]); hv2 = sigf(ao[2])*tanhf_(c2); \
    c3 = sigf(af[3])*c3 + sigf(ai[3])*tanhf_(ag[3]); hv3 = sigf(ao[3])*tanhf_(c3); \
    H[par^1][lk*4+0][u] = (_Float16)hv0; \
    H[par^1][lk*4+1][u] = (_Float16)hv1; \
    H[par^1][lk*4+2][u] = (_Float16)hv2; \
    H[par^1][lk*4+3][u] = (_Float16)hv3; \
    if (u < 100){ \
      hseq[hb0 + ((long)(lk*4+0)*256 + ttc)*100 + u] = hv0; \
      hseq[hb0 + ((long)(lk*4+1)*256 + ttc)*100 + u] = hv1; \
      hseq[hb0 + ((long)(lk*4+2)*256 + ttc)*100 + u] = hv2; \
      hseq[hb0 + ((long)(lk*4+3)*256 + ttc)*100 + u] = hv3; \
    } \
    asm volatile("s_waitcnt lgkmcnt(0)" ::: "memory"); \
    __builtin_amdgcn_s_barrier(); \
    __builtin_amdgcn_sched_barrier(0); \
  }

  for (int t = 0; t < 256; t += 2){
    STEPB(pA, t)
    STEPB(pB, t+1)
  }
#undef STEPB
#undef CVT4
#undef MF
#undef PREF
}

// ---------------- Kernel 5: emissions em[p][25] = b_tag + concat(h_f,h_b)[p] @ W_tag
__global__ __launch_bounds__(256) void k_em(const float* __restrict__ hseq,
    const float* __restrict__ Wtag, const float* __restrict__ btag,
    float* __restrict__ em){
  __shared__ float hrow[8][200];
  __shared__ float Ws[5000];
  int tid = threadIdx.x;
  for (int i=tid;i<5000;i+=256) Ws[i] = Wtag[i];
  int p0 = blockIdx.x*8;
  for (int i=tid;i<8*200;i+=256){
    int r = i/200; int k = i - r*200;
    int p = p0+r;
    hrow[r][k] = (k<100) ? hseq[(long)p*100+k] : hseq[((long)NWORDS + p)*100 + (k-100)];
  }
  __syncthreads();
  int r = tid>>5; int c = tid&31;
  if (c<25){
    float acc = btag[c];
    for (int k=0;k<200;k++) acc += hrow[r][k]*Ws[k*25+c];
    em[(long)(p0+r)*25 + c] = acc;
  }
}

// ---------------- Kernel 6: CRF per sequence: part[s] = logZ - gold.
__global__ __launch_bounds__(64) void k_crf(const float* __restrict__ em,
    const int* __restrict__ tag, const float* __restrict__ trans,
    const float* __restrict__ start, const float* __restrict__ endv,
    float* __restrict__ part){
  int s = blockIdx.x;
  int lane = threadIdx.x;
  int j = lane & 31; int kg = lane >> 5;
  int k0 = kg ? 13 : 0; int kcnt = kg ? 12 : 13;
  const float* emb = em + (long)s*256*25;
  float tr[13];
  #pragma unroll
  for (int kk=0;kk<13;kk++){
    int k = k0+kk;
    tr[kk] = (k<25 && j<25) ? trans[k*25+j] : 0.f;
  }
  float alpha = (j<25) ? (start[j] + emb[j]) : -1e30f;
  float enext = (j<25) ? emb[25 + j] : 0.f;
  for (int t=1;t<256;t++){
    float ecur = enext;
    if (t<255 && j<25) enext = emb[(t+1)*25 + j];
    float m = -1e30f;
    #pragma unroll
    for (int kk=0;kk<13;kk++){
      if (kk<kcnt){
        float a = __shfl(alpha, k0+kk, 64);
        m = fmaxf(m, a + tr[kk]);
      }
    }
    m = fmaxf(m, __shfl_xor(m, 32, 64));
    float ssum = 0.f;
    #pragma unroll
    for (int kk=0;kk<13;kk++){
      if (kk<kcnt){
        float a = __shfl(alpha, k0+kk, 64);
        ssum += __expf(a + tr[kk] - m);
      }
    }
    ssum += __shfl_xor(ssum, 32, 64);
    float anew = __logf(ssum) + m + ecur;
    alpha = (j<25) ? anew : -1e30f;
  }
  float val = (j<25 && kg==0) ? (alpha + endv[j]) : -1e30f;
  float m2 = -1e30f;
  for (int k=0;k<25;k++) m2 = fmaxf(m2, __shfl(val, k, 64));
  float s2 = 0.f;
  for (int k=0;k<25;k++) s2 += __expf(__shfl(val, k, 64) - m2);
  float logZ = __logf(s2) + m2;
  const int* tg = tag + s*256;
  float gp = 0.f;
  for (int t=lane; t<256; t+=64){
    int a = tg[t];
    gp += emb[t*25 + a];
    if (t<255) gp += trans[a*25 + tg[t+1]];
  }
  #pragma unroll
  for (int off=32; off; off>>=1) gp += __shfl_xor(gp, off, 64);
  if (lane==0){
    float gold = gp + start[tg[0]] + endv[tg[255]];
    part[s] = logZ - gold;
  }
}

// ---------------- Kernel 7: final reduce
__global__ __launch_bounds__(64) void k_red(const float* __restrict__ part, float* __restrict__ out){
  float v = part[threadIdx.x];
  #pragma unroll
  for (int off=32; off; off>>=1) v += __shfl_xor(v, off, 64);
  if (threadIdx.x==0) out[0] = v;
}

extern "C" void kernel_launch(void* const* d_in, const int* in_sizes, int n_in,
                              void* d_out, int out_size, void* d_ws, size_t ws_size,
                              hipStream_t stream){
  const int* tok          = (const int*)d_in[0];
  const int* tagp         = (const int*)d_in[1];
  const int* char_tensor  = (const int*)d_in[3];
  const int* char_lengths = (const int*)d_in[4];
  const int* recover      = (const int*)d_in[5];
  const float* word_emb = (const float*)d_in[6];
  const float* char_emb = (const float*)d_in[7];
  const float* cWih_f=(const float*)d_in[8];  const float* cWhh_f=(const float*)d_in[9];  const float* cb_f=(const float*)d_in[10];
  const float* cWih_b=(const float*)d_in[11]; const float* cWhh_b=(const float*)d_in[12]; const float* cb_b=(const float*)d_in[13];
  const float* wWih_f=(const float*)d_in[14]; const float* wWhh_f=(const float*)d_in[15]; const float* wb_f=(const float*)d_in[16];
  const float* wWih_b=(const float*)d_in[17]; const float* wWhh_b=(const float*)d_in[18]; const float* wb_b=(const float*)d_in[19];
  const float* W_tag=(const float*)d_in[20];  const float* b_tag=(const float*)d_in[21];
  const float* trans=(const float*)d_in[22];  const float* startv=(const float*)d_in[23]; const float* endv=(const float*)d_in[24];

  float* ws  = (float*)d_ws;
  float* gxc = ws;                            // [0, 25600)
  float* cf  = ws + 25600;                    // [25600, 943104)
  float* x   = ws + 943104;                   // [943104, 3400704)
  _Float16* gx16 = (_Float16*)(ws + 3400704); // 13107200 halves -> [3400704, 9954304)
  _Float16* gxP  = (_Float16*)(ws + 9954304); // 14680064 halves -> [9954304, 17294336)
  float* hseq= ws + 17294336;                 // [17294336, 20571136)
  float* em  = ws + 943104;                   // overlays x (dead after k_wih)
  float* part= ws + 20571136;                 // 64
  _Float16* WhP = (_Float16*)(ws + 20571200); // 114688 halves (total ~82.5 MB)
  float* out = (float*)d_out;

  k_gxc   <<<100, 256, 0, stream>>>(char_emb, cWih_f, cb_f, cWih_b, cb_b, gxc);
  k_prep  <<<448, 256, 0, stream>>>(wWhh_f, wWhh_b, WhP);
  k_char  <<<6554,512, 0, stream>>>(char_tensor, char_lengths, cWhh_f, cWhh_b, gxc, cf);
  k_buildx<<<9600,256, 0, stream>>>(tok, recover, word_emb, cf, x);
  k_wih   <<<2048,256, 0, stream>>>(x, wWih_f, wb_f, wWih_b, wb_b, gx16);
  k_perm  <<<2048,448, 0, stream>>>(gx16, gxP);
  k_wlstm <<<8,   448, 0, stream>>>(gxP, WhP, hseq);
  k_em    <<<2048,256, 0, stream>>>(hseq, W_tag, b_tag, em);
  k_crf   <<<64,  64,  0, stream>>>(em, tagp, trans, startv, endv, part);
  k_red   <<<1,   64,  0, stream>>>(part, out);
}

// Round 12
// 834.141 us; speedup vs baseline: 1.0043x; 1.0043x over previous
//
#include <hip/hip_runtime.h>
#include <hip/hip_bf16.h>
#include <hip/hip_fp16.h>

// Problem constants
#define NB 64
#define NT 256
#define TC 16
#define NL 25
#define NWORDS 16384   // NB*NT
#define DWd 150        // word-LSTM input dim
#define WEd 100
#define WPB 5          // words per k_char block

typedef _Float16 f16x8 __attribute__((ext_vector_type(8)));
typedef _Float16 f16x4 __attribute__((ext_vector_type(4)));
typedef float    f32x4 __attribute__((ext_vector_type(4)));

__device__ __forceinline__ float sigf(float x){ return __fdividef(1.f, 1.f + __expf(-x)); }
__device__ __forceinline__ float tanhf_(float x){
    float ax = fabsf(x);
    float e = __expf(-2.f*ax);                 // e in (0,1], overflow-safe
    float r = (1.f - e) * __fdividef(1.f, 1.f + e);
    return copysignf(r, x);
}

// ---------------- Kernel 0: gxc[(c,d)][col] = cb_d[col] + sum_k char_emb[c][k]*cWih_d[k*100+col]
__global__ void k_gxc(const float* __restrict__ char_emb,
                      const float* __restrict__ cWih_f, const float* __restrict__ cb_f,
                      const float* __restrict__ cWih_b, const float* __restrict__ cb_b,
                      float* __restrict__ gxc){
  int i = blockIdx.x*blockDim.x + threadIdx.x;
  if (i >= 128*2*100) return;
  int col = i % 100; int d = (i/100) & 1; int c = i/200;
  const float* Wih = d ? cWih_b : cWih_f;
  const float* bb  = d ? cb_b  : cb_f;
  float acc = bb[col];
  #pragma unroll
  for (int k=0;k<25;k++) acc += char_emb[c*25+k]*Wih[k*100+col];
  gxc[i] = acc;
}

// ---------------- Kernel 0b: WhP[d][k(128)][colp(512)] f16, gate-padded (128 cols/gate), zero pads
__global__ void k_prep(const float* __restrict__ whf, const float* __restrict__ whb,
                       _Float16* __restrict__ WhP){
  int i = blockIdx.x*blockDim.x + threadIdx.x;
  if (i >= 2*128*512) return;
  int colp = i % 512; int k = (i/512) % 128; int d = i/(512*128);
  int g = colp >> 7, uu = colp & 127;
  const float* W = d ? whb : whf;
  WhP[i] = (k < 100 && uu < 100) ? (_Float16)W[k*400 + g*100 + uu] : (_Float16)0.f;
}

// ---------------- Kernel 1: char BiLSTM, thread = (word_in_block, gate_col).
__global__ __launch_bounds__(512) void k_char(const int* __restrict__ char_tensor,
   const int* __restrict__ char_lengths,
   const float* __restrict__ cWhh_f, const float* __restrict__ cWhh_b,
   const float* __restrict__ gxc, float* __restrict__ cf){
  __shared__ float h_lds[WPB][28];
  __shared__ float act[WPB][100];
  __shared__ int   chars[WPB][TC];
  __shared__ int   lens[WPB];
  int tid = threadIdx.x;
  int d  = blockIdx.x & 1;
  int wb = blockIdx.x >> 1;
  int w0 = wb*WPB;
  if (tid < WPB*TC){
    int ww = w0 + tid/TC;
    int cw = ww < NWORDS ? ww : NWORDS-1;
    chars[tid/TC][tid%TC] = char_tensor[cw*TC + (tid%TC)];
  }
  if (tid < WPB){
    int ww = w0 + tid;
    lens[tid] = char_lengths[ww < NWORDS ? ww : NWORDS-1];
  }
  int wsub = tid/100;
  int j    = tid - wsub*100;
  bool gate_thr = tid < WPB*100;
  const float* Wh = d ? cWhh_b : cWhh_f;
  float wcol[25];
  if (gate_thr){
    #pragma unroll
    for (int k=0;k<25;k++) wcol[k] = Wh[k*100 + j];
  }
  if (gate_thr && j < 28) h_lds[wsub][j] = 0.f;
  float c_reg = 0.f, h_last = 0.f;
  __syncthreads();
  int len = gate_thr ? lens[wsub] : 1;
  bool isg = (j >= 50) && (j < 75);
  float g_all[TC];
  if (gate_thr){
    #pragma unroll
    for (int t=0;t<TC;t++){
      int ci = d ? (len-1-t) : t;
      if (ci < 0 || ci >= TC) ci = 0;
      int cidx = chars[wsub][ci];
      g_all[t] = gxc[(size_t)(cidx*2+d)*100 + j];
    }
  }
  for (int t=0;t<TC;t++){
    if (gate_thr){
      float a = g_all[t];
      const float4* h4 = (const float4*)h_lds[wsub];
      #pragma unroll
      for (int kq=0;kq<6;kq++){
        float4 hq = h4[kq];
        a += hq.x*wcol[4*kq] + hq.y*wcol[4*kq+1] + hq.z*wcol[4*kq+2] + hq.w*wcol[4*kq+3];
      }
      a += h_lds[wsub][24]*wcol[24];
      act[wsub][j] = isg ? tanhf_(a) : sigf(a);
    }
    __syncthreads();
    if (gate_thr && j < 25 && t < len){
      float si = act[wsub][j], sf = act[wsub][25+j], sg = act[wsub][50+j], so = act[wsub][75+j];
      c_reg = sf*c_reg + si*sg;
      float hv = so*tanhf_(c_reg);
      h_lds[wsub][j] = hv;
      h_last = hv;
    }
    __syncthreads();
  }
  if (gate_thr && j < 25){
    int w = w0 + wsub;
    if (w < NWORDS) cf[(size_t)w*56 + d*28 + j] = h_last;
  }
}

// ---------------- Kernel 2: x[p][150] = word_emb[tok[p]] ++ cf[recover[p]] (cf stride 56)
__global__ void k_buildx(const int* __restrict__ tok, const int* __restrict__ recover,
                         const float* __restrict__ word_emb, const float* __restrict__ cf,
                         float* __restrict__ x){
  long i = (long)blockIdx.x*blockDim.x + threadIdx.x;
  if (i >= (long)NWORDS*DWd) return;
  int p = (int)(i/DWd); int e = (int)(i - (long)p*DWd);
  float v;
  if (e < WEd) v = word_emb[(long)tok[p]*WEd + e];
  else {
    int cidx = e - WEd;
    int dd = cidx / 25; int uu = cidx - dd*25;
    v = cf[(size_t)recover[p]*56 + dd*28 + uu];
  }
  x[i] = v;
}

// ---------------- Kernel 3: gx16[d][p][400] (f16) = wb_d + x[p] @ wWih_d
__global__ __launch_bounds__(256) void k_wih(const float* __restrict__ x,
    const float* __restrict__ Wf, const float* __restrict__ bf,
    const float* __restrict__ Wb, const float* __restrict__ bbias,
    _Float16* __restrict__ gx16){
  __shared__ float As[150][36];
  int tid = threadIdx.x;
  int m0 = (blockIdx.x>>2)*32;
  int nt = blockIdx.x & 3;
  int n0 = nt*256;
  for (int i=tid; i<32*150; i+=256){
    int r = i/150; int k = i - r*150;
    As[k][r] = x[(long)(m0+r)*150 + k];
  }
  __syncthreads();
  int tn = tid & 31; int tm = tid >> 5;
  int j0 = n0 + tn*8;
  bool colok = j0 < 800;
  int d = (j0 >= 400) ? 1 : 0;
  const float* W = d ? Wb : Wf;
  int jc = j0 - d*400;
  float acc[4][8];
  #pragma unroll
  for (int mi=0;mi<4;mi++)
    #pragma unroll
    for (int ni=0;ni<8;ni++) acc[mi][ni]=0.f;
  if (colok){
    for (int k=0;k<150;k++){
      float4 b0 = *(const float4*)&W[k*400 + jc];
      float4 b1 = *(const float4*)&W[k*400 + jc + 4];
      float4 a4 = *(const float4*)&As[k][tm*4];
      float av[4] = {a4.x,a4.y,a4.z,a4.w};
      float bv[8] = {b0.x,b0.y,b0.z,b0.w,b1.x,b1.y,b1.z,b1.w};
      #pragma unroll
      for (int mi=0;mi<4;mi++)
        #pragma unroll
        for (int ni=0;ni<8;ni++) acc[mi][ni] += av[mi]*bv[ni];
    }
    const float* bptr = d ? bbias : bf;
    float bias[8];
    #pragma unroll
    for (int ni=0;ni<8;ni++) bias[ni] = bptr[jc+ni];
    #pragma unroll
    for (int mi=0;mi<4;mi++){
      int p = m0 + tm*4 + mi;
      f16x8 h8;
      #pragma unroll
      for (int ni=0;ni<8;ni++) h8[ni] = (_Float16)(acc[mi][ni] + bias[ni]);
      *(f16x8*)&gx16[((long)d*NWORDS + p)*400 + jc] = h8;
    }
  }
}

// ---------------- Kernel 3b: permute gx16 -> gxP[dg][step][colp(512)][seq(16)] f16
__global__ __launch_bounds__(512) void k_perm(const _Float16* __restrict__ gx16,
                                              _Float16* __restrict__ gxP){
  int bid = blockIdx.x;            // (d*4+grp)*256 + step
  int step = bid & 255; int dg = bid >> 8; int d = dg >> 2; int grp = dg & 3;
  int t = d ? (255 - step) : step;
  int colp = threadIdx.x;          // 0..511
  int g = colp >> 7, uu = colp & 127;
  f16x8 v0, v1;
  #pragma unroll
  for (int q=0;q<8;q++){ v0[q] = (_Float16)0.f; v1[q] = (_Float16)0.f; }
  if (uu < 100){
    int col = g*100 + uu;
    const _Float16* src = gx16 + ((size_t)d*NWORDS + (size_t)grp*16*256 + t)*400 + col;
    #pragma unroll
    for (int q=0;q<8;q++) v0[q] = src[(size_t)q*256*400];
    #pragma unroll
    for (int q=0;q<8;q++) v1[q] = src[(size_t)(q+8)*256*400];
  }
  _Float16* dst = gxP + ((size_t)bid*512 + colp)*16;
  *(f16x8*)dst = v0;
  *(f16x8*)(dst+8) = v1;
}

// ---------------- Kernel 4: word LSTM recurrence v11 — MFMA-batched, swizzled LDS.
// 8 blocks (dir x 4 seq-groups) x 512 thr (8 waves, even 2/SIMD). Per step:
// G(16x512) = H(16x128,f16) @ WhP(128x512,f16) via 16 MFMA/wave, gx as C-init.
// H in LDS with chunk-XOR swizzle (phys16Bchunk = logical ^ row) -> <=2-way
// (free) on both ds_read_b128 A-frags and ds_write_b16 h-updates. One raw
// s_barrier/step preceded by lgkmcnt(0) ONLY: prefetch loads + hseq stores
// stay in flight across barriers; loads precede stores so compiler's counted
// vmcnt for P never waits on stores.
__global__ __launch_bounds__(512, 1) void k_wlstm(const _Float16* __restrict__ gxP,
     const _Float16* __restrict__ WhP, float* __restrict__ hseq){
  __shared__ __align__(16) _Float16 H[2*2048];   // [parity][16 rows][128 cols], swizzled
  int tid = threadIdx.x;
  int lane = tid & 63, w = tid >> 6;          // w = 0..7
  int bid = blockIdx.x;                       // d*4 + grp
  int d = bid >> 2; int grp = bid & 3;
  int li = lane & 15, lk = lane >> 4;         // li: M/N idx, lk: k-group
  int u = 16*w + li;                          // unit col within gate, 0..127
  // B-fragments (gate-stationary weights; verified layout from v10)
  f16x8 Bf[4][4];
  {
    const _Float16* Wd = WhP + (size_t)d*128*512;
    #pragma unroll
    for (int g=0; g<4; ++g){
      int colp = 128*g + u;
      #pragma unroll
      for (int kk=0; kk<4; ++kk){
        f16x8 b;
        #pragma unroll
        for (int j=0;j<8;j++) b[j] = Wd[(size_t)(kk*32 + lk*8 + j)*512 + colp];
        Bf[g][kk] = b;
      }
    }
  }
  for (int i=tid; i<2*2048; i+=512) H[i] = (_Float16)0.f;
  // Precomputed swizzled offsets (halves within one parity buffer of 2048)
  int aoff0 = li*128 + (((0*4+lk) ^ li) << 3);
  int aoff1 = li*128 + (((1*4+lk) ^ li) << 3);
  int aoff2 = li*128 + (((2*4+lk) ^ li) << 3);
  int aoff3 = li*128 + (((3*4+lk) ^ li) << 3);
  int woff0 = (lk*4+0)*128 + ((((u>>3) ^ (lk*4+0)) & 15) << 3) + (u & 7);
  int woff1 = (lk*4+1)*128 + ((((u>>3) ^ (lk*4+1)) & 15) << 3) + (u & 7);
  int woff2 = (lk*4+2)*128 + ((((u>>3) ^ (lk*4+2)) & 15) << 3) + (u & 7);
  int woff3 = (lk*4+3)*128 + ((((u>>3) ^ (lk*4+3)) & 15) << 3) + (u & 7);
  float c0=0.f, c1=0.f, c2=0.f, c3=0.f;
  const _Float16* gxb = gxP + (size_t)bid*256*8192;
  long hb0 = ((long)d*NWORDS + (long)grp*16*256)*100;
  f16x4 pA[4], pB[4];
#define PREF(P, ST) { const _Float16* _r = gxb + (size_t)(ST)*8192 + (size_t)lk*4; \
    P[0] = *(const f16x4*)(_r + (size_t)(0*128 + u)*16); \
    P[1] = *(const f16x4*)(_r + (size_t)(1*128 + u)*16); \
    P[2] = *(const f16x4*)(_r + (size_t)(2*128 + u)*16); \
    P[3] = *(const f16x4*)(_r + (size_t)(3*128 + u)*16); }
  PREF(pA, 0)
  PREF(pB, 1)
  __syncthreads();

#define MF(A,B,C) __builtin_amdgcn_mfma_f32_16x16x32_f16(A, B, C, 0, 0, 0)
#define CVT4(P) (f32x4){(float)(P)[0], (float)(P)[1], (float)(P)[2], (float)(P)[3]}
#define STEPB(P, T) { \
    const int par = (T) & 1; \
    const _Float16* Hb = H + par*2048; \
    f16x8 a0 = *(const f16x8*)(Hb + aoff0); \
    f16x8 a1 = *(const f16x8*)(Hb + aoff1); \
    f16x8 a2 = *(const f16x8*)(Hb + aoff2); \
    f16x8 a3 = *(const f16x8*)(Hb + aoff3); \
    f32x4 ai = CVT4(P[0]), af = CVT4(P[1]), ag = CVT4(P[2]), ao = CVT4(P[3]); \
    ai = MF(a0, Bf[0][0], ai); ai = MF(a1, Bf[0][1], ai); ai = MF(a2, Bf[0][2], ai); ai = MF(a3, Bf[0][3], ai); \
    af = MF(a0, Bf[1][0], af); af = MF(a1, Bf[1][1], af); af = MF(a2, Bf[1][2], af); af = MF(a3, Bf[1][3], af); \
    ag = MF(a0, Bf[2][0], ag); ag = MF(a1, Bf[2][1], ag); ag = MF(a2, Bf[2][2], ag); ag = MF(a3, Bf[2][3], ag); \
    ao = MF(a0, Bf[3][0], ao); ao = MF(a1, Bf[3][1], ao); ao = MF(a2, Bf[3][2], ao); ao = MF(a3, Bf[3][3], ao); \
    if ((T)+2 < 256) PREF(P, (T)+2) \
    _Float16* Hw = H + (par^1)*2048; \
    int ttc = d ? (255-(T)) : (T); \
    float hv0, hv1, hv2, hv3; \
    c0 = sigf(af[0])*c0 + sigf(ai[0])*tanhf_(ag[0]); hv0 = sigf(ao[0])*tanhf_(c0); \
    c1 = sigf(af[1])*c1 + sigf(ai[1])*tanhf_(ag[1]); hv1 = sigf(ao[1])*tanhf_(c1); \
    c2 = sigf(af[2])*c2 + sigf(ai[2])*tanhf_(ag[2]); hv2 = sigf(ao[2])*tanhf_(c2); \
    c3 = sigf(af[3])*c3 + sigf(ai[3])*tanhf_(ag[3]); hv3 = sigf(ao[3])*tanhf_(c3); \
    Hw[woff0] = (_Float16)hv0; \
    Hw[woff1] = (_Float16)hv1; \
    Hw[woff2] = (_Float16)hv2; \
    Hw[woff3] = (_Float16)hv3; \
    if (u < 100){ \
      hseq[hb0 + ((long)(lk*4+0)*256 + ttc)*100 + u] = hv0; \
      hseq[hb0 + ((long)(lk*4+1)*256 + ttc)*100 + u] = hv1; \
      hseq[hb0 + ((long)(lk*4+2)*256 + ttc)*100 + u] = hv2; \
      hseq[hb0 + ((long)(lk*4+3)*256 + ttc)*100 + u] = hv3; \
    } \
    asm volatile("s_waitcnt lgkmcnt(0)" ::: "memory"); \
    __builtin_amdgcn_s_barrier(); \
  }

  for (int t = 0; t < 256; t += 2){
    STEPB(pA, t)
    STEPB(pB, t+1)
  }
#undef STEPB
#undef CVT4
#undef MF
#undef PREF
}

// ---------------- Kernel 5: emissions em[p][25] = b_tag + concat(h_f,h_b)[p] @ W_tag
__global__ __launch_bounds__(256) void k_em(const float* __restrict__ hseq,
    const float* __restrict__ Wtag, const float* __restrict__ btag,
    float* __restrict__ em){
  __shared__ float hrow[8][200];
  __shared__ float Ws[5000];
  int tid = threadIdx.x;
  for (int i=tid;i<5000;i+=256) Ws[i] = Wtag[i];
  int p0 = blockIdx.x*8;
  for (int i=tid;i<8*200;i+=256){
    int r = i/200; int k = i - r*200;
    int p = p0+r;
    hrow[r][k] = (k<100) ? hseq[(long)p*100+k] : hseq[((long)NWORDS + p)*100 + (k-100)];
  }
  __syncthreads();
  int r = tid>>5; int c = tid&31;
  if (c<25){
    float acc = btag[c];
    for (int k=0;k<200;k++) acc += hrow[r][k]*Ws[k*25+c];
    em[(long)(p0+r)*25 + c] = acc;
  }
}

// ---------------- Kernel 6: CRF per sequence: part[s] = logZ - gold.
__global__ __launch_bounds__(64) void k_crf(const float* __restrict__ em,
    const int* __restrict__ tag, const float* __restrict__ trans,
    const float* __restrict__ start, const float* __restrict__ endv,
    float* __restrict__ part){
  int s = blockIdx.x;
  int lane = threadIdx.x;
  int j = lane & 31; int kg = lane >> 5;
  int k0 = kg ? 13 : 0; int kcnt = kg ? 12 : 13;
  const float* emb = em + (long)s*256*25;
  float tr[13];
  #pragma unroll
  for (int kk=0;kk<13;kk++){
    int k = k0+kk;
    tr[kk] = (k<25 && j<25) ? trans[k*25+j] : 0.f;
  }
  float alpha = (j<25) ? (start[j] + emb[j]) : -1e30f;
  float enext = (j<25) ? emb[25 + j] : 0.f;
  for (int t=1;t<256;t++){
    float ecur = enext;
    if (t<255 && j<25) enext = emb[(t+1)*25 + j];
    float m = -1e30f;
    #pragma unroll
    for (int kk=0;kk<13;kk++){
      if (kk<kcnt){
        float a = __shfl(alpha, k0+kk, 64);
        m = fmaxf(m, a + tr[kk]);
      }
    }
    m = fmaxf(m, __shfl_xor(m, 32, 64));
    float ssum = 0.f;
    #pragma unroll
    for (int kk=0;kk<13;kk++){
      if (kk<kcnt){
        float a = __shfl(alpha, k0+kk, 64);
        ssum += __expf(a + tr[kk] - m);
      }
    }
    ssum += __shfl_xor(ssum, 32, 64);
    float anew = __logf(ssum) + m + ecur;
    alpha = (j<25) ? anew : -1e30f;
  }
  float val = (j<25 && kg==0) ? (alpha + endv[j]) : -1e30f;
  float m2 = -1e30f;
  for (int k=0;k<25;k++) m2 = fmaxf(m2, __shfl(val, k, 64));
  float s2 = 0.f;
  for (int k=0;k<25;k++) s2 += __expf(__shfl(val, k, 64) - m2);
  float logZ = __logf(s2) + m2;
  const int* tg = tag + s*256;
  float gp = 0.f;
  for (int t=lane; t<256; t+=64){
    int a = tg[t];
    gp += emb[t*25 + a];
    if (t<255) gp += trans[a*25 + tg[t+1]];
  }
  #pragma unroll
  for (int off=32; off; off>>=1) gp += __shfl_xor(gp, off, 64);
  if (lane==0){
    float gold = gp + start[tg[0]] + endv[tg[255]];
    part[s] = logZ - gold;
  }
}

// ---------------- Kernel 7: final reduce
__global__ __launch_bounds__(64) void k_red(const float* __restrict__ part, float* __restrict__ out){
  float v = part[threadIdx.x];
  #pragma unroll
  for (int off=32; off; off>>=1) v += __shfl_xor(v, off, 64);
  if (threadIdx.x==0) out[0] = v;
}

extern "C" void kernel_launch(void* const* d_in, const int* in_sizes, int n_in,
                              void* d_out, int out_size, void* d_ws, size_t ws_size,
                              hipStream_t stream){
  const int* tok          = (const int*)d_in[0];
  const int* tagp         = (const int*)d_in[1];
  const int* char_tensor  = (const int*)d_in[3];
  const int* char_lengths = (const int*)d_in[4];
  const int* recover      = (const int*)d_in[5];
  const float* word_emb = (const float*)d_in[6];
  const float* char_emb = (const float*)d_in[7];
  const float* cWih_f=(const float*)d_in[8];  const float* cWhh_f=(const float*)d_in[9];  const float* cb_f=(const float*)d_in[10];
  const float* cWih_b=(const float*)d_in[11]; const float* cWhh_b=(const float*)d_in[12]; const float* cb_b=(const float*)d_in[13];
  const float* wWih_f=(const float*)d_in[14]; const float* wWhh_f=(const float*)d_in[15]; const float* wb_f=(const float*)d_in[16];
  const float* wWih_b=(const float*)d_in[17]; const float* wWhh_b=(const float*)d_in[18]; const float* wb_b=(const float*)d_in[19];
  const float* W_tag=(const float*)d_in[20];  const float* b_tag=(const float*)d_in[21];
  const float* trans=(const float*)d_in[22];  const float* startv=(const float*)d_in[23]; const float* endv=(const float*)d_in[24];

  float* ws  = (float*)d_ws;
  float* gxc = ws;                            // [0, 25600)
  float* cf  = ws + 25600;                    // [25600, 943104)
  float* x   = ws + 943104;                   // [943104, 3400704)
  _Float16* gx16 = (_Float16*)(ws + 3400704); // 13107200 halves -> [3400704, 9954304)
  _Float16* gxP  = (_Float16*)(ws + 9954304); // 16777216 halves -> [9954304, 18342912)
  float* hseq= ws + 3400704;                  // overlays gx16 (dead after k_perm), 3276800
  float* em  = ws + 943104;                   // overlays x (dead after k_wih), 409600
  float* part= ws + 18342912;                 // 64
  _Float16* WhP = (_Float16*)(ws + 18342976); // 131072 halves  (high water ~73.6 MB)
  float* out = (float*)d_out;

  k_gxc   <<<100, 256, 0, stream>>>(char_emb, cWih_f, cb_f, cWih_b, cb_b, gxc);
  k_prep  <<<512, 256, 0, stream>>>(wWhh_f, wWhh_b, WhP);
  k_char  <<<6554,512, 0, stream>>>(char_tensor, char_lengths, cWhh_f, cWhh_b, gxc, cf);
  k_buildx<<<9600,256, 0, stream>>>(tok, recover, word_emb, cf, x);
  k_wih   <<<2048,256, 0, stream>>>(x, wWih_f, wb_f, wWih_b, wb_b, gx16);
  k_perm  <<<2048,512, 0, stream>>>(gx16, gxP);
  k_wlstm <<<8,   512, 0, stream>>>(gxP, WhP, hseq);
  k_em    <<<2048,256, 0, stream>>>(hseq, W_tag, b_tag, em);
  k_crf   <<<64,  64,  0, stream>>>(em, tagp, trans, startv, endv, part);
  k_red   <<<1,   64,  0, stream>>>(part, out);
}

// Round 13
// 619.493 us; speedup vs baseline: 1.3523x; 1.3465x over previous
//
#include <hip/hip_runtime.h>
#include <hip/hip_bf16.h>

// Problem constants
#define NB 64
#define NT 256
#define TC 16
#define NL 25
#define NWORDS 16384   // NB*NT
#define DWd 150        // word-LSTM input dim
#define WEd 100
#define WPB 5          // words per k_char block

__device__ __forceinline__ float sigf(float x){ return __fdividef(1.f, 1.f + __expf(-x)); }
__device__ __forceinline__ float tanhf_(float x){
    float ax = fabsf(x);
    float e = __expf(-2.f*ax);                 // e in (0,1], overflow-safe
    float r = (1.f - e) * __fdividef(1.f, 1.f + e);
    return copysignf(r, x);
}

// ---------------- Kernel 0: gxc[(c,d)][col] = cb_d[col] + sum_k char_emb[c][k]*cWih_d[k*100+col]
__global__ void k_gxc(const float* __restrict__ char_emb,
                      const float* __restrict__ cWih_f, const float* __restrict__ cb_f,
                      const float* __restrict__ cWih_b, const float* __restrict__ cb_b,
                      float* __restrict__ gxc){
  int i = blockIdx.x*blockDim.x + threadIdx.x;
  if (i >= 128*2*100) return;
  int col = i % 100; int d = (i/100) & 1; int c = i/200;
  const float* Wih = d ? cWih_b : cWih_f;
  const float* bb  = d ? cb_b  : cb_f;
  float acc = bb[col];
  #pragma unroll
  for (int k=0;k<25;k++) acc += char_emb[c*25+k]*Wih[k*100+col];
  gxc[i] = acc;
}

// ---------------- Kernel 1: char BiLSTM, thread = (word_in_block, gate_col).
__global__ __launch_bounds__(512) void k_char(const int* __restrict__ char_tensor,
   const int* __restrict__ char_lengths,
   const float* __restrict__ cWhh_f, const float* __restrict__ cWhh_b,
   const float* __restrict__ gxc, float* __restrict__ cf){
  __shared__ float h_lds[WPB][28];
  __shared__ float act[WPB][100];
  __shared__ int   chars[WPB][TC];
  __shared__ int   lens[WPB];
  int tid = threadIdx.x;
  int d  = blockIdx.x & 1;
  int wb = blockIdx.x >> 1;
  int w0 = wb*WPB;
  if (tid < WPB*TC){
    int ww = w0 + tid/TC;
    int cw = ww < NWORDS ? ww : NWORDS-1;
    chars[tid/TC][tid%TC] = char_tensor[cw*TC + (tid%TC)];
  }
  if (tid < WPB){
    int ww = w0 + tid;
    lens[tid] = char_lengths[ww < NWORDS ? ww : NWORDS-1];
  }
  int wsub = tid/100;
  int j    = tid - wsub*100;
  bool gate_thr = tid < WPB*100;
  const float* Wh = d ? cWhh_b : cWhh_f;
  float wcol[25];
  if (gate_thr){
    #pragma unroll
    for (int k=0;k<25;k++) wcol[k] = Wh[k*100 + j];
  }
  if (gate_thr && j < 28) h_lds[wsub][j] = 0.f;
  float c_reg = 0.f, h_last = 0.f;
  __syncthreads();
  int len = gate_thr ? lens[wsub] : 1;
  bool isg = (j >= 50) && (j < 75);
  float g_all[TC];
  if (gate_thr){
    #pragma unroll
    for (int t=0;t<TC;t++){
      int ci = d ? (len-1-t) : t;
      if (ci < 0 || ci >= TC) ci = 0;
      int cidx = chars[wsub][ci];
      g_all[t] = gxc[(size_t)(cidx*2+d)*100 + j];
    }
  }
  for (int t=0;t<TC;t++){
    if (gate_thr){
      float a = g_all[t];
      const float4* h4 = (const float4*)h_lds[wsub];
      #pragma unroll
      for (int kq=0;kq<6;kq++){
        float4 hq = h4[kq];
        a += hq.x*wcol[4*kq] + hq.y*wcol[4*kq+1] + hq.z*wcol[4*kq+2] + hq.w*wcol[4*kq+3];
      }
      a += h_lds[wsub][24]*wcol[24];
      act[wsub][j] = isg ? tanhf_(a) : sigf(a);
    }
    __syncthreads();
    if (gate_thr && j < 25 && t < len){
      float si = act[wsub][j], sf = act[wsub][25+j], sg = act[wsub][50+j], so = act[wsub][75+j];
      c_reg = sf*c_reg + si*sg;
      float hv = so*tanhf_(c_reg);
      h_lds[wsub][j] = hv;
      h_last = hv;
    }
    __syncthreads();
  }
  if (gate_thr && j < 25){
    int w = w0 + wsub;
    if (w < NWORDS) cf[(size_t)w*56 + d*28 + j] = h_last;
  }
}

// ---------------- Kernel 3: gx[d][p][400] = wb_d + [word_emb[tok[p]] ++ cf[recover[p]]] @ wWih_d
// buildx FUSED into the A-tile staging (no x round-trip). fp32 tiled, M=16384,N=800,K=150.
__global__ __launch_bounds__(256) void k_wih(const int* __restrict__ tok,
    const int* __restrict__ recover,
    const float* __restrict__ word_emb, const float* __restrict__ cf,
    const float* __restrict__ Wf, const float* __restrict__ bf,
    const float* __restrict__ Wb, const float* __restrict__ bbias,
    float* __restrict__ gx){
  __shared__ float As[150][36];
  __shared__ int toks[32], recs[32];
  int tid = threadIdx.x;
  int m0 = (blockIdx.x>>2)*32;
  int nt = blockIdx.x & 3;
  int n0 = nt*256;
  if (tid < 32) toks[tid] = tok[m0 + tid];
  else if (tid < 64) recs[tid-32] = recover[m0 + tid - 32];
  __syncthreads();
  for (int i=tid; i<32*150; i+=256){
    int r = i/150; int k = i - r*150;
    float v;
    if (k < WEd) v = word_emb[(long)toks[r]*WEd + k];
    else {
      int ci = k - WEd;            // 0..49
      int dd = ci/25; int uu = ci - dd*25;
      v = cf[(size_t)recs[r]*56 + dd*28 + uu];
    }
    As[k][r] = v;
  }
  __syncthreads();
  int tn = tid & 31; int tm = tid >> 5;
  int j0 = n0 + tn*8;
  bool colok = j0 < 800;
  int d = (j0 >= 400) ? 1 : 0;
  const float* W = d ? Wb : Wf;
  int jc = j0 - d*400;
  float acc[4][8];
  #pragma unroll
  for (int mi=0;mi<4;mi++)
    #pragma unroll
    for (int ni=0;ni<8;ni++) acc[mi][ni]=0.f;
  if (colok){
    for (int k=0;k<150;k++){
      float4 b0 = *(const float4*)&W[k*400 + jc];
      float4 b1 = *(const float4*)&W[k*400 + jc + 4];
      float4 a4 = *(const float4*)&As[k][tm*4];
      float av[4] = {a4.x,a4.y,a4.z,a4.w};
      float bv[8] = {b0.x,b0.y,b0.z,b0.w,b1.x,b1.y,b1.z,b1.w};
      #pragma unroll
      for (int mi=0;mi<4;mi++)
        #pragma unroll
        for (int ni=0;ni<8;ni++) acc[mi][ni] += av[mi]*bv[ni];
    }
    const float* bptr = d ? bbias : bf;
    float bias[8];
    #pragma unroll
    for (int ni=0;ni<8;ni++) bias[ni] = bptr[jc+ni];
    #pragma unroll
    for (int mi=0;mi<4;mi++){
      int p = m0 + tm*4 + mi;
      float* orow = gx + ((long)d*NWORDS + p)*400 + jc;
      #pragma unroll
      for (int ni=0;ni<8;ni++) orow[ni] = acc[mi][ni] + bias[ni];
    }
  }
}

// ---------------- Kernel 4: word LSTM recurrence (v4, proven 229us / absmax 0).
// block = (seq, dir), 448 threads (7 waves). Thread j<400 owns ONE gate column:
// wreg[100] staged global->LDS->reg. h broadcast via 25 uniform ds_read_b128.
// 2 barriers/step, single-buffered h/act (race-free).
__global__ __launch_bounds__(448, 2) void k_wlstm(const float* __restrict__ gx,
     const float* __restrict__ Whf, const float* __restrict__ Whb,
     float* __restrict__ hseq){
  __shared__ float wstage[10000];   // 25 rows x 400 cols, 40KB chunk
  __shared__ float h_lds[100];
  __shared__ float act[400];
  int tid = threadIdx.x;
  int s = blockIdx.x & 63; int d = blockIdx.x >> 6;
  const float* Wh = d ? Whb : Whf;
  int j = tid;
  bool colthr = j < 400;
  float wreg[100];
  #pragma unroll
  for (int ch=0; ch<4; ch++){
    for (int i=tid; i<2500; i+=448)
      ((float4*)wstage)[i] = ((const float4*)(Wh + ch*10000))[i];
    __syncthreads();
    if (colthr){
      #pragma unroll
      for (int kk=0;kk<25;kk++) wreg[ch*25+kk] = wstage[kk*400 + j];
    }
    __syncthreads();
  }
  if (tid < 100) h_lds[tid] = 0.f;
  float c_reg = 0.f;
  const float* gxd = gx + ((long)d*NWORDS + (long)s*256)*400;
  bool isg = (j >= 200) && (j < 300);
  __syncthreads();
  float gnext = 0.f;
  if (colthr) gnext = gxd[(d?255:0)*400 + j];
  for (int t=0;t<256;t++){
    float gcur = gnext;
    if (colthr && t+1 < 256){
      int tn = d ? (255-(t+1)) : (t+1);
      gnext = gxd[tn*400 + j];
    }
    if (colthr){
      float a = gcur;
      const float4* h4 = (const float4*)h_lds;
      #pragma unroll
      for (int kq=0;kq<25;kq++){
        float4 hq = h4[kq];
        a += hq.x*wreg[4*kq] + hq.y*wreg[4*kq+1] + hq.z*wreg[4*kq+2] + hq.w*wreg[4*kq+3];
      }
      act[j] = isg ? tanhf_(a) : sigf(a);
    }
    __syncthreads();   // act visible; all h_lds reads of this step done
    if (tid < 100){
      float si = act[tid], sf = act[100+tid], sg = act[200+tid], so = act[300+tid];
      c_reg = sf*c_reg + si*sg;
      float hv = so*tanhf_(c_reg);
      h_lds[tid] = hv;
      int ttc = d ? (255-t) : t;
      hseq[((long)d*NWORDS + s*256 + ttc)*100 + tid] = hv;
    }
    __syncthreads();   // new h visible
  }
}

// ---------------- Kernel 5: emissions em[p][25] = b_tag + concat(h_f,h_b)[p] @ W_tag
__global__ __launch_bounds__(256) void k_em(const float* __restrict__ hseq,
    const float* __restrict__ Wtag, const float* __restrict__ btag,
    float* __restrict__ em){
  __shared__ float hrow[8][200];
  __shared__ float Ws[5000];
  int tid = threadIdx.x;
  for (int i=tid;i<5000;i+=256) Ws[i] = Wtag[i];
  int p0 = blockIdx.x*8;
  for (int i=tid;i<8*200;i+=256){
    int r = i/200; int k = i - r*200;
    int p = p0+r;
    hrow[r][k] = (k<100) ? hseq[(long)p*100+k] : hseq[((long)NWORDS + p)*100 + (k-100)];
  }
  __syncthreads();
  int r = tid>>5; int c = tid&31;
  if (c<25){
    float acc = btag[c];
    for (int k=0;k<200;k++) acc += hrow[r][k]*Ws[k*25+c];
    em[(long)(p0+r)*25 + c] = acc;
  }
}

// ---------------- Kernel 6: CRF per sequence: part[s] = logZ - gold.
__global__ __launch_bounds__(64) void k_crf(const float* __restrict__ em,
    const int* __restrict__ tag, const float* __restrict__ trans,
    const float* __restrict__ start, const float* __restrict__ endv,
    float* __restrict__ part){
  int s = blockIdx.x;
  int lane = threadIdx.x;
  int j = lane & 31; int kg = lane >> 5;
  int k0 = kg ? 13 : 0; int kcnt = kg ? 12 : 13;
  const float* emb = em + (long)s*256*25;
  float tr[13];
  #pragma unroll
  for (int kk=0;kk<13;kk++){
    int k = k0+kk;
    tr[kk] = (k<25 && j<25) ? trans[k*25+j] : 0.f;
  }
  float alpha = (j<25) ? (start[j] + emb[j]) : -1e30f;
  float enext = (j<25) ? emb[25 + j] : 0.f;
  for (int t=1;t<256;t++){
    float ecur = enext;
    if (t<255 && j<25) enext = emb[(t+1)*25 + j];
    float m = -1e30f;
    #pragma unroll
    for (int kk=0;kk<13;kk++){
      if (kk<kcnt){
        float a = __shfl(alpha, k0+kk, 64);
        m = fmaxf(m, a + tr[kk]);
      }
    }
    m = fmaxf(m, __shfl_xor(m, 32, 64));
    float ssum = 0.f;
    #pragma unroll
    for (int kk=0;kk<13;kk++){
      if (kk<kcnt){
        float a = __shfl(alpha, k0+kk, 64);
        ssum += __expf(a + tr[kk] - m);
      }
    }
    ssum += __shfl_xor(ssum, 32, 64);
    float anew = __logf(ssum) + m + ecur;
    alpha = (j<25) ? anew : -1e30f;
  }
  float val = (j<25 && kg==0) ? (alpha + endv[j]) : -1e30f;
  float m2 = -1e30f;
  for (int k=0;k<25;k++) m2 = fmaxf(m2, __shfl(val, k, 64));
  float s2 = 0.f;
  for (int k=0;k<25;k++) s2 += __expf(__shfl(val, k, 64) - m2);
  float logZ = __logf(s2) + m2;
  const int* tg = tag + s*256;
  float gp = 0.f;
  for (int t=lane; t<256; t+=64){
    int a = tg[t];
    gp += emb[t*25 + a];
    if (t<255) gp += trans[a*25 + tg[t+1]];
  }
  #pragma unroll
  for (int off=32; off; off>>=1) gp += __shfl_xor(gp, off, 64);
  if (lane==0){
    float gold = gp + start[tg[0]] + endv[tg[255]];
    part[s] = logZ - gold;
  }
}

// ---------------- Kernel 7: final reduce
__global__ __launch_bounds__(64) void k_red(const float* __restrict__ part, float* __restrict__ out){
  float v = part[threadIdx.x];
  #pragma unroll
  for (int off=32; off; off>>=1) v += __shfl_xor(v, off, 64);
  if (threadIdx.x==0) out[0] = v;
}

extern "C" void kernel_launch(void* const* d_in, const int* in_sizes, int n_in,
                              void* d_out, int out_size, void* d_ws, size_t ws_size,
                              hipStream_t stream){
  const int* tok          = (const int*)d_in[0];
  const int* tagp         = (const int*)d_in[1];
  const int* char_tensor  = (const int*)d_in[3];
  const int* char_lengths = (const int*)d_in[4];
  const int* recover      = (const int*)d_in[5];
  const float* word_emb = (const float*)d_in[6];
  const float* char_emb = (const float*)d_in[7];
  const float* cWih_f=(const float*)d_in[8];  const float* cWhh_f=(const float*)d_in[9];  const float* cb_f=(const float*)d_in[10];
  const float* cWih_b=(const float*)d_in[11]; const float* cWhh_b=(const float*)d_in[12]; const float* cb_b=(const float*)d_in[13];
  const float* wWih_f=(const float*)d_in[14]; const float* wWhh_f=(const float*)d_in[15]; const float* wb_f=(const float*)d_in[16];
  const float* wWih_b=(const float*)d_in[17]; const float* wWhh_b=(const float*)d_in[18]; const float* wb_b=(const float*)d_in[19];
  const float* W_tag=(const float*)d_in[20];  const float* b_tag=(const float*)d_in[21];
  const float* trans=(const float*)d_in[22];  const float* startv=(const float*)d_in[23]; const float* endv=(const float*)d_in[24];

  float* ws  = (float*)d_ws;
  float* gxc = ws;                 // [0, 25600)
  float* cf  = ws + 25600;         // [25600, 943104)
  float* gx  = ws + 943104;        // [943104, 14050304)
  float* hseq= ws + 14050304;      // [14050304, 17327104)
  float* em  = ws;                 // overlays gxc+cf (dead after k_wih), 409600
  float* part= ws + 17327104;      // 64   (high water ~69.3 MB)
  float* out = (float*)d_out;

  k_gxc   <<<100, 256, 0, stream>>>(char_emb, cWih_f, cb_f, cWih_b, cb_b, gxc);
  k_char  <<<6554,512, 0, stream>>>(char_tensor, char_lengths, cWhh_f, cWhh_b, gxc, cf);
  k_wih   <<<2048,256, 0, stream>>>(tok, recover, word_emb, cf, wWih_f, wb_f, wWih_b, wb_b, gx);
  k_wlstm <<<128, 448, 0, stream>>>(gx, wWhh_f, wWhh_b, hseq);
  k_em    <<<2048,256, 0, stream>>>(hseq, W_tag, b_tag, em);
  k_crf   <<<64,  64,  0, stream>>>(em, tagp, trans, startv, endv, part);
  k_red   <<<1,   64,  0, stream>>>(part, out);
}

// Round 14
// 566.201 us; speedup vs baseline: 1.4796x; 1.0941x over previous
//
#include <hip/hip_runtime.h>
#include <hip/hip_bf16.h>

// Problem constants
#define NB 64
#define NT 256
#define TC 16
#define NL 25
#define NWORDS 16384   // NB*NT
#define DWd 150        // word-LSTM input dim
#define WEd 100
#define WPB 5          // words per k_char block

__device__ __forceinline__ float sigf(float x){ return __fdividef(1.f, 1.f + __expf(-x)); }
__device__ __forceinline__ float tanhf_(float x){
    float ax = fabsf(x);
    float e = __expf(-2.f*ax);                 // e in (0,1], overflow-safe
    float r = (1.f - e) * __fdividef(1.f, 1.f + e);
    return copysignf(r, x);
}
__device__ __forceinline__ float RL(float v, int k){
    return __int_as_float(__builtin_amdgcn_readlane(__float_as_int(v), k));
}

// ---------------- Kernel 0: gxc[(c,d)][col] = cb_d[col] + sum_k char_emb[c][k]*cWih_d[k*100+col]
__global__ void k_gxc(const float* __restrict__ char_emb,
                      const float* __restrict__ cWih_f, const float* __restrict__ cb_f,
                      const float* __restrict__ cWih_b, const float* __restrict__ cb_b,
                      float* __restrict__ gxc){
  int i = blockIdx.x*blockDim.x + threadIdx.x;
  if (i >= 128*2*100) return;
  int col = i % 100; int d = (i/100) & 1; int c = i/200;
  const float* Wih = d ? cWih_b : cWih_f;
  const float* bb  = d ? cb_b  : cb_f;
  float acc = bb[col];
  #pragma unroll
  for (int k=0;k<25;k++) acc += char_emb[c*25+k]*Wih[k*100+col];
  gxc[i] = acc;
}

// ---------------- Kernel 1: char BiLSTM, thread = (word_in_block, gate_col).
// gcur/gnext named-register prefetch (NO runtime-indexed array -> no scratch).
__global__ __launch_bounds__(512) void k_char(const int* __restrict__ char_tensor,
   const int* __restrict__ char_lengths,
   const float* __restrict__ cWhh_f, const float* __restrict__ cWhh_b,
   const float* __restrict__ gxc, float* __restrict__ cf){
  __shared__ float h_lds[WPB][28];
  __shared__ float act[WPB][100];
  __shared__ int   chars[WPB][TC];
  __shared__ int   lens[WPB];
  int tid = threadIdx.x;
  int d  = blockIdx.x & 1;
  int wb = blockIdx.x >> 1;
  int w0 = wb*WPB;
  if (tid < WPB*TC){
    int ww = w0 + tid/TC;
    int cw = ww < NWORDS ? ww : NWORDS-1;
    chars[tid/TC][tid%TC] = char_tensor[cw*TC + (tid%TC)];
  }
  if (tid < WPB){
    int ww = w0 + tid;
    lens[tid] = char_lengths[ww < NWORDS ? ww : NWORDS-1];
  }
  int wsub = tid/100;
  int j    = tid - wsub*100;
  bool gate_thr = tid < WPB*100;
  const float* Wh = d ? cWhh_b : cWhh_f;
  float wcol[25];
  if (gate_thr){
    #pragma unroll
    for (int k=0;k<25;k++) wcol[k] = Wh[k*100 + j];
  }
  if (gate_thr && j < 28) h_lds[wsub][j] = 0.f;
  float c_reg = 0.f, h_last = 0.f;
  __syncthreads();
  int len = gate_thr ? lens[wsub] : 1;
  bool isg = (j >= 50) && (j < 75);
  float gnext = 0.f;
  if (gate_thr){
    int ci = d ? (len-1) : 0;
    if (ci < 0 || ci >= TC) ci = 0;
    gnext = gxc[(size_t)(chars[wsub][ci]*2+d)*100 + j];
  }
  for (int t=0;t<TC;t++){
    float gcur = gnext;
    if (gate_thr && t+1 < TC){
      int ci = d ? (len-2-t) : (t+1);
      if (ci < 0 || ci >= TC) ci = 0;
      gnext = gxc[(size_t)(chars[wsub][ci]*2+d)*100 + j];
    }
    if (gate_thr){
      float a = gcur;
      const float4* h4 = (const float4*)h_lds[wsub];
      #pragma unroll
      for (int kq=0;kq<6;kq++){
        float4 hq = h4[kq];
        a += hq.x*wcol[4*kq] + hq.y*wcol[4*kq+1] + hq.z*wcol[4*kq+2] + hq.w*wcol[4*kq+3];
      }
      a += h_lds[wsub][24]*wcol[24];
      act[wsub][j] = isg ? tanhf_(a) : sigf(a);
    }
    __syncthreads();
    if (gate_thr && j < 25 && t < len){
      float si = act[wsub][j], sf = act[wsub][25+j], sg = act[wsub][50+j], so = act[wsub][75+j];
      c_reg = sf*c_reg + si*sg;
      float hv = so*tanhf_(c_reg);
      h_lds[wsub][j] = hv;
      h_last = hv;
    }
    __syncthreads();
  }
  if (gate_thr && j < 25){
    int w = w0 + wsub;
    if (w < NWORDS) cf[(size_t)w*56 + d*28 + j] = h_last;
  }
}

// ---------------- Kernel 3: gx[d][p][400] = wb_d + [word_emb[tok[p]] ++ cf[recover[p]]] @ wWih_d
// BM=64 (halves 4x-redundant B re-reads), acc 8x8, buildx fused into A staging.
__global__ __launch_bounds__(256) void k_wih(const int* __restrict__ tok,
    const int* __restrict__ recover,
    const float* __restrict__ word_emb, const float* __restrict__ cf,
    const float* __restrict__ Wf, const float* __restrict__ bf,
    const float* __restrict__ Wb, const float* __restrict__ bbias,
    float* __restrict__ gx){
  __shared__ float As[150][72];
  __shared__ int toks[64], recs[64];
  int tid = threadIdx.x;
  int m0 = (blockIdx.x>>2)*64;
  int nt = blockIdx.x & 3;
  int n0 = nt*256;
  if (tid < 64) toks[tid] = tok[m0 + tid];
  else if (tid < 128) recs[tid-64] = recover[m0 + tid - 64];
  __syncthreads();
  for (int i=tid; i<64*150; i+=256){
    int r = i/150; int k = i - r*150;
    float v;
    if (k < WEd) v = word_emb[(long)toks[r]*WEd + k];
    else {
      int ci = k - WEd;
      int dd = ci/25; int uu = ci - dd*25;
      v = cf[(size_t)recs[r]*56 + dd*28 + uu];
    }
    As[k][r] = v;
  }
  __syncthreads();
  int tn = tid & 31; int tm = tid >> 5;
  int j0 = n0 + tn*8;
  bool colok = j0 < 800;
  int d = (j0 >= 400) ? 1 : 0;
  const float* W = d ? Wb : Wf;
  int jc = j0 - d*400;
  float acc[8][8];
  #pragma unroll
  for (int mi=0;mi<8;mi++)
    #pragma unroll
    for (int ni=0;ni<8;ni++) acc[mi][ni]=0.f;
  if (colok){
    for (int k=0;k<150;k++){
      float4 b0 = *(const float4*)&W[k*400 + jc];
      float4 b1 = *(const float4*)&W[k*400 + jc + 4];
      float4 a0 = *(const float4*)&As[k][tm*8];
      float4 a1 = *(const float4*)&As[k][tm*8+4];
      float av[8] = {a0.x,a0.y,a0.z,a0.w,a1.x,a1.y,a1.z,a1.w};
      float bv[8] = {b0.x,b0.y,b0.z,b0.w,b1.x,b1.y,b1.z,b1.w};
      #pragma unroll
      for (int mi=0;mi<8;mi++)
        #pragma unroll
        for (int ni=0;ni<8;ni++) acc[mi][ni] += av[mi]*bv[ni];
    }
    const float* bptr = d ? bbias : bf;
    float bias[8];
    #pragma unroll
    for (int ni=0;ni<8;ni++) bias[ni] = bptr[jc+ni];
    #pragma unroll
    for (int mi=0;mi<8;mi++){
      int p = m0 + tm*8 + mi;
      float* orow = gx + ((long)d*NWORDS + p)*400 + jc;
      #pragma unroll
      for (int ni=0;ni<8;ni++) orow[ni] = acc[mi][ni] + bias[ni];
    }
  }
}

// ---------------- Kernel 4: word LSTM recurrence (v4, proven 229us / absmax 0).
__global__ __launch_bounds__(448, 2) void k_wlstm(const float* __restrict__ gx,
     const float* __restrict__ Whf, const float* __restrict__ Whb,
     float* __restrict__ hseq){
  __shared__ float wstage[10000];   // 25 rows x 400 cols, 40KB chunk
  __shared__ float h_lds[100];
  __shared__ float act[400];
  int tid = threadIdx.x;
  int s = blockIdx.x & 63; int d = blockIdx.x >> 6;
  const float* Wh = d ? Whb : Whf;
  int j = tid;
  bool colthr = j < 400;
  float wreg[100];
  #pragma unroll
  for (int ch=0; ch<4; ch++){
    for (int i=tid; i<2500; i+=448)
      ((float4*)wstage)[i] = ((const float4*)(Wh + ch*10000))[i];
    __syncthreads();
    if (colthr){
      #pragma unroll
      for (int kk=0;kk<25;kk++) wreg[ch*25+kk] = wstage[kk*400 + j];
    }
    __syncthreads();
  }
  if (tid < 100) h_lds[tid] = 0.f;
  float c_reg = 0.f;
  const float* gxd = gx + ((long)d*NWORDS + (long)s*256)*400;
  bool isg = (j >= 200) && (j < 300);
  __syncthreads();
  float gnext = 0.f;
  if (colthr) gnext = gxd[(d?255:0)*400 + j];
  for (int t=0;t<256;t++){
    float gcur = gnext;
    if (colthr && t+1 < 256){
      int tn = d ? (255-(t+1)) : (t+1);
      gnext = gxd[tn*400 + j];
    }
    if (colthr){
      float a = gcur;
      const float4* h4 = (const float4*)h_lds;
      #pragma unroll
      for (int kq=0;kq<25;kq++){
        float4 hq = h4[kq];
        a += hq.x*wreg[4*kq] + hq.y*wreg[4*kq+1] + hq.z*wreg[4*kq+2] + hq.w*wreg[4*kq+3];
      }
      act[j] = isg ? tanhf_(a) : sigf(a);
    }
    __syncthreads();   // act visible; all h_lds reads of this step done
    if (tid < 100){
      float si = act[tid], sf = act[100+tid], sg = act[200+tid], so = act[300+tid];
      c_reg = sf*c_reg + si*sg;
      float hv = so*tanhf_(c_reg);
      h_lds[tid] = hv;
      int ttc = d ? (255-t) : t;
      hseq[((long)d*NWORDS + s*256 + ttc)*100 + tid] = hv;
    }
    __syncthreads();   // new h visible
  }
}

// ---------------- Kernel 5: emissions em[p][25] = b_tag + concat(h_f,h_b)[p] @ W_tag
__global__ __launch_bounds__(256) void k_em(const float* __restrict__ hseq,
    const float* __restrict__ Wtag, const float* __restrict__ btag,
    float* __restrict__ em){
  __shared__ float hrow[8][200];
  __shared__ float Ws[5000];
  int tid = threadIdx.x;
  for (int i=tid;i<5000;i+=256) Ws[i] = Wtag[i];
  int p0 = blockIdx.x*8;
  for (int i=tid;i<8*200;i+=256){
    int r = i/200; int k = i - r*200;
    int p = p0+r;
    hrow[r][k] = (k<100) ? hseq[(long)p*100+k] : hseq[((long)NWORDS + p)*100 + (k-100)];
  }
  __syncthreads();
  int r = tid>>5; int c = tid&31;
  if (c<25){
    float acc = btag[c];
    for (int k=0;k<200;k++) acc += hrow[r][k]*Ws[k*25+c];
    em[(long)(p0+r)*25 + c] = acc;
  }
}

// ---------------- Kernel 6: CRF per sequence. Lane-per-tag, constant-lane
// readlane broadcasts (no ds_bpermute), baseline-shift logsumexp (exact:
// base cancels; exp args bounded by alpha spread ~±3).
__global__ __launch_bounds__(64) void k_crf(const float* __restrict__ em,
    const int* __restrict__ tag, const float* __restrict__ trans,
    const float* __restrict__ start, const float* __restrict__ endv,
    float* __restrict__ part){
  int s = blockIdx.x;
  int lane = threadIdx.x;
  const float* emb = em + (long)s*256*25;
  float tr[25];
  #pragma unroll
  for (int k=0;k<25;k++) tr[k] = (lane<25) ? trans[k*25+lane] : 0.f;
  float alpha = (lane<25) ? (start[lane] + emb[lane]) : 0.f;
  float enext = (lane<25) ? emb[25+lane] : 0.f;
  for (int t=1;t<256;t++){
    float ecur = enext;
    if (t<255 && lane<25) enext = emb[(t+1)*25 + lane];
    float base = RL(alpha, 0);
    float s0=0.f,s1=0.f,s2=0.f,s3=0.f,s4=0.f;
    #pragma unroll
    for (int k=0;k<5;k++) s0 += __expf(RL(alpha,k)    + tr[k]    - base);
    #pragma unroll
    for (int k=0;k<5;k++) s1 += __expf(RL(alpha,5+k)  + tr[5+k]  - base);
    #pragma unroll
    for (int k=0;k<5;k++) s2 += __expf(RL(alpha,10+k) + tr[10+k] - base);
    #pragma unroll
    for (int k=0;k<5;k++) s3 += __expf(RL(alpha,15+k) + tr[15+k] - base);
    #pragma unroll
    for (int k=0;k<5;k++) s4 += __expf(RL(alpha,20+k) + tr[20+k] - base);
    float ssum = ((s0+s1)+(s2+s3))+s4;
    alpha = __logf(ssum) + base + ecur;
  }
  float val = (lane<25) ? (alpha + endv[lane]) : -1e30f;
  float m2 = -1e30f;
  #pragma unroll
  for (int k=0;k<25;k++) m2 = fmaxf(m2, RL(val,k));
  float s2s = 0.f;
  #pragma unroll
  for (int k=0;k<25;k++) s2s += __expf(RL(val,k) - m2);
  float logZ = __logf(s2s) + m2;
  // gold path score (all 64 lanes)
  const int* tg = tag + s*256;
  float gp = 0.f;
  for (int t=lane; t<256; t+=64){
    int a = tg[t];
    gp += emb[t*25 + a];
    if (t<255) gp += trans[a*25 + tg[t+1]];
  }
  #pragma unroll
  for (int off=32; off; off>>=1) gp += __shfl_xor(gp, off, 64);
  if (lane==0){
    float gold = gp + start[tg[0]] + endv[tg[255]];
    part[s] = logZ - gold;
  }
}

// ---------------- Kernel 7: final reduce
__global__ __launch_bounds__(64) void k_red(const float* __restrict__ part, float* __restrict__ out){
  float v = part[threadIdx.x];
  #pragma unroll
  for (int off=32; off; off>>=1) v += __shfl_xor(v, off, 64);
  if (threadIdx.x==0) out[0] = v;
}

extern "C" void kernel_launch(void* const* d_in, const int* in_sizes, int n_in,
                              void* d_out, int out_size, void* d_ws, size_t ws_size,
                              hipStream_t stream){
  const int* tok          = (const int*)d_in[0];
  const int* tagp         = (const int*)d_in[1];
  const int* char_tensor  = (const int*)d_in[3];
  const int* char_lengths = (const int*)d_in[4];
  const int* recover      = (const int*)d_in[5];
  const float* word_emb = (const float*)d_in[6];
  const float* char_emb = (const float*)d_in[7];
  const float* cWih_f=(const float*)d_in[8];  const float* cWhh_f=(const float*)d_in[9];  const float* cb_f=(const float*)d_in[10];
  const float* cWih_b=(const float*)d_in[11]; const float* cWhh_b=(const float*)d_in[12]; const float* cb_b=(const float*)d_in[13];
  const float* wWih_f=(const float*)d_in[14]; const float* wWhh_f=(const float*)d_in[15]; const float* wb_f=(const float*)d_in[16];
  const float* wWih_b=(const float*)d_in[17]; const float* wWhh_b=(const float*)d_in[18]; const float* wb_b=(const float*)d_in[19];
  const float* W_tag=(const float*)d_in[20];  const float* b_tag=(const float*)d_in[21];
  const float* trans=(const float*)d_in[22];  const float* startv=(const float*)d_in[23]; const float* endv=(const float*)d_in[24];

  float* ws  = (float*)d_ws;
  float* gxc = ws;                 // [0, 25600)
  float* cf  = ws + 25600;         // [25600, 943104)
  float* gx  = ws + 943104;        // [943104, 14050304)
  float* hseq= ws + 14050304;      // [14050304, 17327104)
  float* em  = ws;                 // overlays gxc+cf (dead after k_wih), 409600
  float* part= ws + 17327104;      // 64   (high water ~69.3 MB)
  float* out = (float*)d_out;

  k_gxc   <<<100, 256, 0, stream>>>(char_emb, cWih_f, cb_f, cWih_b, cb_b, gxc);
  k_char  <<<6554,512, 0, stream>>>(char_tensor, char_lengths, cWhh_f, cWhh_b, gxc, cf);
  k_wih   <<<1024,256, 0, stream>>>(tok, recover, word_emb, cf, wWih_f, wb_f, wWih_b, wb_b, gx);
  k_wlstm <<<128, 448, 0, stream>>>(gx, wWhh_f, wWhh_b, hseq);
  k_em    <<<2048,256, 0, stream>>>(hseq, W_tag, b_tag, em);
  k_crf   <<<64,  64,  0, stream>>>(em, tagp, trans, startv, endv, part);
  k_red   <<<1,   64,  0, stream>>>(part, out);
}

// Round 15
// 540.305 us; speedup vs baseline: 1.5505x; 1.0479x over previous
//
#include <hip/hip_runtime.h>
#include <hip/hip_bf16.h>

// Problem constants
#define NB 64
#define NT 256
#define TC 16
#define NL 25
#define NWORDS 16384   // NB*NT
#define DWd 150        // word-LSTM input dim
#define WEd 100
#define WPB 5          // words per k_char block

__device__ __forceinline__ float sigf(float x){ return __fdividef(1.f, 1.f + __expf(-x)); }
__device__ __forceinline__ float tanhf_(float x){
    float ax = fabsf(x);
    float e = __expf(-2.f*ax);                 // e in (0,1], overflow-safe
    float r = (1.f - e) * __fdividef(1.f, 1.f + e);
    return copysignf(r, x);
}
__device__ __forceinline__ float RL(float v, int k){
    return __int_as_float(__builtin_amdgcn_readlane(__float_as_int(v), k));
}

// ---------------- Sort kernels: bucket words by char length (16 buckets).
// Output widx[] is a permutation of 0..16383 grouped by length. Per-word results
// are order-independent -> deterministic output despite atomic ordering.
__global__ void k_zero(int* __restrict__ meta){
  if (threadIdx.x < 34) meta[threadIdx.x] = 0;
}
__global__ __launch_bounds__(256) void k_hist(const int* __restrict__ char_lengths,
                                              int* __restrict__ hist){
  __shared__ int lh[16];
  int tid = threadIdx.x;
  if (tid < 16) lh[tid] = 0;
  __syncthreads();
  int w = blockIdx.x*256 + tid;
  atomicAdd(&lh[char_lengths[w]-1], 1);
  __syncthreads();
  if (tid < 16) atomicAdd(&hist[tid], lh[tid]);
}
__global__ void k_scan(const int* __restrict__ hist, int* __restrict__ cursor){
  if (threadIdx.x == 0){
    int acc = 0;
    for (int i=0;i<16;i++){ cursor[i] = acc; acc += hist[i]; }
  }
}
__global__ __launch_bounds__(256) void k_scatter(const int* __restrict__ char_lengths,
                                                 int* __restrict__ cursor,
                                                 int* __restrict__ widx){
  __shared__ int lh[16], lbase[16];
  int tid = threadIdx.x;
  if (tid < 16) lh[tid] = 0;
  __syncthreads();
  int w = blockIdx.x*256 + tid;
  int len = char_lengths[w]-1;
  int lrank = atomicAdd(&lh[len], 1);
  __syncthreads();
  if (tid < 16) lbase[tid] = atomicAdd(&cursor[tid], lh[tid]);
  __syncthreads();
  widx[lbase[len] + lrank] = w;
}

// ---------------- Kernel 0: gxc[(c,d)][col] = cb_d[col] + sum_k char_emb[c][k]*cWih_d[k*100+col]
__global__ void k_gxc(const float* __restrict__ char_emb,
                      const float* __restrict__ cWih_f, const float* __restrict__ cb_f,
                      const float* __restrict__ cWih_b, const float* __restrict__ cb_b,
                      float* __restrict__ gxc){
  int i = blockIdx.x*blockDim.x + threadIdx.x;
  if (i >= 128*2*100) return;
  int col = i % 100; int d = (i/100) & 1; int c = i/200;
  const float* Wih = d ? cWih_b : cWih_f;
  const float* bb  = d ? cb_b  : cb_f;
  float acc = bb[col];
  #pragma unroll
  for (int k=0;k<25;k++) acc += char_emb[c*25+k]*Wih[k*100+col];
  gxc[i] = acc;
}

// ---------------- Kernel 1: char BiLSTM over length-sorted words.
// Block words share ~one length -> loop to lmax (~len) instead of 16.
__global__ __launch_bounds__(512) void k_char(const int* __restrict__ char_tensor,
   const int* __restrict__ char_lengths, const int* __restrict__ widx,
   const float* __restrict__ cWhh_f, const float* __restrict__ cWhh_b,
   const float* __restrict__ gxc, float* __restrict__ cf){
  __shared__ float h_lds[WPB][28];
  __shared__ float act[WPB][100];
  __shared__ int   chars[WPB][TC];
  __shared__ int   lens[WPB];
  __shared__ int   wids[WPB];
  int tid = threadIdx.x;
  int d  = blockIdx.x & 1;
  int wb = blockIdx.x >> 1;
  int w0 = wb*WPB;
  if (tid < WPB){
    int slot = w0 + tid; if (slot > NWORDS-1) slot = NWORDS-1;
    wids[tid] = widx[slot];
  }
  __syncthreads();
  if (tid < WPB*TC){
    int ww = wids[tid/TC];
    chars[tid/TC][tid%TC] = char_tensor[ww*TC + (tid%TC)];
  }
  if (tid < WPB) lens[tid] = char_lengths[wids[tid]];
  int wsub = tid/100;
  int j    = tid - wsub*100;
  bool gate_thr = tid < WPB*100;
  const float* Wh = d ? cWhh_b : cWhh_f;
  float wcol[25];
  if (gate_thr){
    #pragma unroll
    for (int k=0;k<25;k++) wcol[k] = Wh[k*100 + j];
  }
  if (gate_thr && j < 28) h_lds[wsub][j] = 0.f;
  float c_reg = 0.f, h_last = 0.f;
  __syncthreads();
  int lmax = lens[0];
  #pragma unroll
  for (int q=1;q<WPB;q++) lmax = max(lmax, lens[q]);
  int len = gate_thr ? lens[wsub] : 1;
  bool isg = (j >= 50) && (j < 75);
  float gnext = 0.f;
  if (gate_thr){
    int ci = d ? (len-1) : 0;
    if (ci < 0 || ci >= TC) ci = 0;
    gnext = gxc[(size_t)(chars[wsub][ci]*2+d)*100 + j];
  }
  for (int t=0;t<lmax;t++){
    float gcur = gnext;
    if (gate_thr && t+1 < TC){
      int ci = d ? (len-2-t) : (t+1);
      if (ci < 0 || ci >= TC) ci = 0;
      gnext = gxc[(size_t)(chars[wsub][ci]*2+d)*100 + j];
    }
    if (gate_thr){
      float a = gcur;
      const float4* h4 = (const float4*)h_lds[wsub];
      #pragma unroll
      for (int kq=0;kq<6;kq++){
        float4 hq = h4[kq];
        a += hq.x*wcol[4*kq] + hq.y*wcol[4*kq+1] + hq.z*wcol[4*kq+2] + hq.w*wcol[4*kq+3];
      }
      a += h_lds[wsub][24]*wcol[24];
      act[wsub][j] = isg ? tanhf_(a) : sigf(a);
    }
    __syncthreads();
    if (gate_thr && j < 25 && t < len){
      float si = act[wsub][j], sf = act[wsub][25+j], sg = act[wsub][50+j], so = act[wsub][75+j];
      c_reg = sf*c_reg + si*sg;
      float hv = so*tanhf_(c_reg);
      h_lds[wsub][j] = hv;
      h_last = hv;
    }
    __syncthreads();
  }
  if (gate_thr && j < 25){
    int w = wids[wsub];
    cf[(size_t)w*56 + d*28 + j] = h_last;
  }
}

// ---------------- Kernel 3: gx[d][p][400] = wb_d + [word_emb[tok[p]] ++ cf[recover[p]]] @ wWih_d
__global__ __launch_bounds__(256) void k_wih(const int* __restrict__ tok,
    const int* __restrict__ recover,
    const float* __restrict__ word_emb, const float* __restrict__ cf,
    const float* __restrict__ Wf, const float* __restrict__ bf,
    const float* __restrict__ Wb, const float* __restrict__ bbias,
    float* __restrict__ gx){
  __shared__ float As[150][72];
  __shared__ int toks[64], recs[64];
  int tid = threadIdx.x;
  int m0 = (blockIdx.x>>2)*64;
  int nt = blockIdx.x & 3;
  int n0 = nt*256;
  if (tid < 64) toks[tid] = tok[m0 + tid];
  else if (tid < 128) recs[tid-64] = recover[m0 + tid - 64];
  __syncthreads();
  for (int i=tid; i<64*150; i+=256){
    int r = i/150; int k = i - r*150;
    float v;
    if (k < WEd) v = word_emb[(long)toks[r]*WEd + k];
    else {
      int ci = k - WEd;
      int dd = ci/25; int uu = ci - dd*25;
      v = cf[(size_t)recs[r]*56 + dd*28 + uu];
    }
    As[k][r] = v;
  }
  __syncthreads();
  int tn = tid & 31; int tm = tid >> 5;
  int j0 = n0 + tn*8;
  bool colok = j0 < 800;
  int d = (j0 >= 400) ? 1 : 0;
  const float* W = d ? Wb : Wf;
  int jc = j0 - d*400;
  float acc[8][8];
  #pragma unroll
  for (int mi=0;mi<8;mi++)
    #pragma unroll
    for (int ni=0;ni<8;ni++) acc[mi][ni]=0.f;
  if (colok){
    for (int k=0;k<150;k++){
      float4 b0 = *(const float4*)&W[k*400 + jc];
      float4 b1 = *(const float4*)&W[k*400 + jc + 4];
      float4 a0 = *(const float4*)&As[k][tm*8];
      float4 a1 = *(const float4*)&As[k][tm*8+4];
      float av[8] = {a0.x,a0.y,a0.z,a0.w,a1.x,a1.y,a1.z,a1.w};
      float bv[8] = {b0.x,b0.y,b0.z,b0.w,b1.x,b1.y,b1.z,b1.w};
      #pragma unroll
      for (int mi=0;mi<8;mi++)
        #pragma unroll
        for (int ni=0;ni<8;ni++) acc[mi][ni] += av[mi]*bv[ni];
    }
    const float* bptr = d ? bbias : bf;
    float bias[8];
    #pragma unroll
    for (int ni=0;ni<8;ni++) bias[ni] = bptr[jc+ni];
    #pragma unroll
    for (int mi=0;mi<8;mi++){
      int p = m0 + tm*8 + mi;
      float* orow = gx + ((long)d*NWORDS + p)*400 + jc;
      #pragma unroll
      for (int ni=0;ni<8;ni++) orow[ni] = acc[mi][ni] + bias[ni];
    }
  }
}

// ---------------- Kernel 4: word LSTM recurrence (v4, proven 229us / absmax 0).
__global__ __launch_bounds__(448, 2) void k_wlstm(const float* __restrict__ gx,
     const float* __restrict__ Whf, const float* __restrict__ Whb,
     float* __restrict__ hseq){
  __shared__ float wstage[10000];   // 25 rows x 400 cols, 40KB chunk
  __shared__ float h_lds[100];
  __shared__ float act[400];
  int tid = threadIdx.x;
  int s = blockIdx.x & 63; int d = blockIdx.x >> 6;
  const float* Wh = d ? Whb : Whf;
  int j = tid;
  bool colthr = j < 400;
  float wreg[100];
  #pragma unroll
  for (int ch=0; ch<4; ch++){
    for (int i=tid; i<2500; i+=448)
      ((float4*)wstage)[i] = ((const float4*)(Wh + ch*10000))[i];
    __syncthreads();
    if (colthr){
      #pragma unroll
      for (int kk=0;kk<25;kk++) wreg[ch*25+kk] = wstage[kk*400 + j];
    }
    __syncthreads();
  }
  if (tid < 100) h_lds[tid] = 0.f;
  float c_reg = 0.f;
  const float* gxd = gx + ((long)d*NWORDS + (long)s*256)*400;
  bool isg = (j >= 200) && (j < 300);
  __syncthreads();
  float gnext = 0.f;
  if (colthr) gnext = gxd[(d?255:0)*400 + j];
  for (int t=0;t<256;t++){
    float gcur = gnext;
    if (colthr && t+1 < 256){
      int tn = d ? (255-(t+1)) : (t+1);
      gnext = gxd[tn*400 + j];
    }
    if (colthr){
      float a = gcur;
      const float4* h4 = (const float4*)h_lds;
      #pragma unroll
      for (int kq=0;kq<25;kq++){
        float4 hq = h4[kq];
        a += hq.x*wreg[4*kq] + hq.y*wreg[4*kq+1] + hq.z*wreg[4*kq+2] + hq.w*wreg[4*kq+3];
      }
      act[j] = isg ? tanhf_(a) : sigf(a);
    }
    __syncthreads();   // act visible; all h_lds reads of this step done
    if (tid < 100){
      float si = act[tid], sf = act[100+tid], sg = act[200+tid], so = act[300+tid];
      c_reg = sf*c_reg + si*sg;
      float hv = so*tanhf_(c_reg);
      h_lds[tid] = hv;
      int ttc = d ? (255-t) : t;
      hseq[((long)d*NWORDS + s*256 + ttc)*100 + tid] = hv;
    }
    __syncthreads();   // new h visible
  }
}

// ---------------- Kernel 5: emissions em[p][25] = b_tag + concat(h_f,h_b)[p] @ W_tag
__global__ __launch_bounds__(256) void k_em(const float* __restrict__ hseq,
    const float* __restrict__ Wtag, const float* __restrict__ btag,
    float* __restrict__ em){
  __shared__ float hrow[8][200];
  __shared__ float Ws[5000];
  int tid = threadIdx.x;
  for (int i=tid;i<5000;i+=256) Ws[i] = Wtag[i];
  int p0 = blockIdx.x*8;
  for (int i=tid;i<8*200;i+=256){
    int r = i/200; int k = i - r*200;
    int p = p0+r;
    hrow[r][k] = (k<100) ? hseq[(long)p*100+k] : hseq[((long)NWORDS + p)*100 + (k-100)];
  }
  __syncthreads();
  int r = tid>>5; int c = tid&31;
  if (c<25){
    float acc = btag[c];
    for (int k=0;k<200;k++) acc += hrow[r][k]*Ws[k*25+c];
    em[(long)(p0+r)*25 + c] = acc;
  }
}

// ---------------- Kernel 6: CRF per sequence. Lane-per-tag, constant-lane
// readlane broadcasts, baseline-shift logsumexp (exact: base cancels).
__global__ __launch_bounds__(64) void k_crf(const float* __restrict__ em,
    const int* __restrict__ tag, const float* __restrict__ trans,
    const float* __restrict__ start, const float* __restrict__ endv,
    float* __restrict__ part){
  int s = blockIdx.x;
  int lane = threadIdx.x;
  const float* emb = em + (long)s*256*25;
  float tr[25];
  #pragma unroll
  for (int k=0;k<25;k++) tr[k] = (lane<25) ? trans[k*25+lane] : 0.f;
  float alpha = (lane<25) ? (start[lane] + emb[lane]) : 0.f;
  float enext = (lane<25) ? emb[25+lane] : 0.f;
  for (int t=1;t<256;t++){
    float ecur = enext;
    if (t<255 && lane<25) enext = emb[(t+1)*25 + lane];
    float base = RL(alpha, 0);
    float s0=0.f,s1=0.f,s2=0.f,s3=0.f,s4=0.f;
    #pragma unroll
    for (int k=0;k<5;k++) s0 += __expf(RL(alpha,k)    + tr[k]    - base);
    #pragma unroll
    for (int k=0;k<5;k++) s1 += __expf(RL(alpha,5+k)  + tr[5+k]  - base);
    #pragma unroll
    for (int k=0;k<5;k++) s2 += __expf(RL(alpha,10+k) + tr[10+k] - base);
    #pragma unroll
    for (int k=0;k<5;k++) s3 += __expf(RL(alpha,15+k) + tr[15+k] - base);
    #pragma unroll
    for (int k=0;k<5;k++) s4 += __expf(RL(alpha,20+k) + tr[20+k] - base);
    float ssum = ((s0+s1)+(s2+s3))+s4;
    alpha = __logf(ssum) + base + ecur;
  }
  float val = (lane<25) ? (alpha + endv[lane]) : -1e30f;
  float m2 = -1e30f;
  #pragma unroll
  for (int k=0;k<25;k++) m2 = fmaxf(m2, RL(val,k));
  float s2s = 0.f;
  #pragma unroll
  for (int k=0;k<25;k++) s2s += __expf(RL(val,k) - m2);
  float logZ = __logf(s2s) + m2;
  const int* tg = tag + s*256;
  float gp = 0.f;
  for (int t=lane; t<256; t+=64){
    int a = tg[t];
    gp += emb[t*25 + a];
    if (t<255) gp += trans[a*25 + tg[t+1]];
  }
  #pragma unroll
  for (int off=32; off; off>>=1) gp += __shfl_xor(gp, off, 64);
  if (lane==0){
    float gold = gp + start[tg[0]] + endv[tg[255]];
    part[s] = logZ - gold;
  }
}

// ---------------- Kernel 7: final reduce
__global__ __launch_bounds__(64) void k_red(const float* __restrict__ part, float* __restrict__ out){
  float v = part[threadIdx.x];
  #pragma unroll
  for (int off=32; off; off>>=1) v += __shfl_xor(v, off, 64);
  if (threadIdx.x==0) out[0] = v;
}

extern "C" void kernel_launch(void* const* d_in, const int* in_sizes, int n_in,
                              void* d_out, int out_size, void* d_ws, size_t ws_size,
                              hipStream_t stream){
  const int* tok          = (const int*)d_in[0];
  const int* tagp         = (const int*)d_in[1];
  const int* char_tensor  = (const int*)d_in[3];
  const int* char_lengths = (const int*)d_in[4];
  const int* recover      = (const int*)d_in[5];
  const float* word_emb = (const float*)d_in[6];
  const float* char_emb = (const float*)d_in[7];
  const float* cWih_f=(const float*)d_in[8];  const float* cWhh_f=(const float*)d_in[9];  const float* cb_f=(const float*)d_in[10];
  const float* cWih_b=(const float*)d_in[11]; const float* cWhh_b=(const float*)d_in[12]; const float* cb_b=(const float*)d_in[13];
  const float* wWih_f=(const float*)d_in[14]; const float* wWhh_f=(const float*)d_in[15]; const float* wb_f=(const float*)d_in[16];
  const float* wWih_b=(const float*)d_in[17]; const float* wWhh_b=(const float*)d_in[18]; const float* wb_b=(const float*)d_in[19];
  const float* W_tag=(const float*)d_in[20];  const float* b_tag=(const float*)d_in[21];
  const float* trans=(const float*)d_in[22];  const float* startv=(const float*)d_in[23]; const float* endv=(const float*)d_in[24];

  float* ws  = (float*)d_ws;
  float* gxc = ws;                 // [0, 25600)
  float* cf  = ws + 25600;         // [25600, 943104)
  float* gx  = ws + 943104;        // [943104, 14050304)
  float* hseq= ws + 14050304;      // [14050304, 17327104)
  float* em  = ws;                 // overlays gxc+cf (dead after k_wih), 409600
  float* part= ws + 17327104;      // 64
  int*   meta= (int*)(ws + 17327168);  // hist[16]+cursor[16]+pad
  int*   widx= meta + 64;              // 16384 ints (high water ~69.4 MB)
  float* out = (float*)d_out;

  k_zero   <<<1,   64,  0, stream>>>(meta);
  k_gxc    <<<100, 256, 0, stream>>>(char_emb, cWih_f, cb_f, cWih_b, cb_b, gxc);
  k_hist   <<<64,  256, 0, stream>>>(char_lengths, meta);
  k_scan   <<<1,   64,  0, stream>>>(meta, meta+16);
  k_scatter<<<64,  256, 0, stream>>>(char_lengths, meta+16, widx);
  k_char   <<<6554,512, 0, stream>>>(char_tensor, char_lengths, widx, cWhh_f, cWhh_b, gxc, cf);
  k_wih    <<<1024,256, 0, stream>>>(tok, recover, word_emb, cf, wWih_f, wb_f, wWih_b, wb_b, gx);
  k_wlstm  <<<128, 448, 0, stream>>>(gx, wWhh_f, wWhh_b, hseq);
  k_em     <<<2048,256, 0, stream>>>(hseq, W_tag, b_tag, em);
  k_crf    <<<64,  64,  0, stream>>>(em, tagp, trans, startv, endv, part);
  k_red    <<<1,   64,  0, stream>>>(part, out);
}

// Round 16
// 536.177 us; speedup vs baseline: 1.5625x; 1.0077x over previous
//
#include <hip/hip_runtime.h>
#include <hip/hip_bf16.h>

// Problem constants
#define NB 64
#define NT 256
#define TC 16
#define NL 25
#define NWORDS 16384   // NB*NT
#define DWd 150        // word-LSTM input dim
#define WEd 100
#define WPB 5          // words per k_char block

__device__ __forceinline__ float sigf(float x){ return __fdividef(1.f, 1.f + __expf(-x)); }
__device__ __forceinline__ float tanhf_(float x){
    float ax = fabsf(x);
    float e = __expf(-2.f*ax);                 // e in (0,1], overflow-safe
    float r = (1.f - e) * __fdividef(1.f, 1.f + e);
    return copysignf(r, x);
}
__device__ __forceinline__ float RL(float v, int k){
    return __int_as_float(__builtin_amdgcn_readlane(__float_as_int(v), k));
}

// ---------------- Sort kernels: bucket words by char length (16 buckets).
__global__ void k_zero(int* __restrict__ meta){
  if (threadIdx.x < 34) meta[threadIdx.x] = 0;
}
__global__ __launch_bounds__(256) void k_hist(const int* __restrict__ char_lengths,
                                              int* __restrict__ hist){
  __shared__ int lh[16];
  int tid = threadIdx.x;
  if (tid < 16) lh[tid] = 0;
  __syncthreads();
  int w = blockIdx.x*256 + tid;
  atomicAdd(&lh[char_lengths[w]-1], 1);
  __syncthreads();
  if (tid < 16) atomicAdd(&hist[tid], lh[tid]);
}
__global__ void k_scan(const int* __restrict__ hist, int* __restrict__ cursor){
  if (threadIdx.x == 0){
    int acc = 0;
    for (int i=0;i<16;i++){ cursor[i] = acc; acc += hist[i]; }
  }
}
__global__ __launch_bounds__(256) void k_scatter(const int* __restrict__ char_lengths,
                                                 int* __restrict__ cursor,
                                                 int* __restrict__ widx){
  __shared__ int lh[16], lbase[16];
  int tid = threadIdx.x;
  if (tid < 16) lh[tid] = 0;
  __syncthreads();
  int w = blockIdx.x*256 + tid;
  int len = char_lengths[w]-1;
  int lrank = atomicAdd(&lh[len], 1);
  __syncthreads();
  if (tid < 16) lbase[tid] = atomicAdd(&cursor[tid], lh[tid]);
  __syncthreads();
  widx[lbase[len] + lrank] = w;
}

// ---------------- Kernel 0: gxc[(c,d)][col] = cb_d[col] + sum_k char_emb[c][k]*cWih_d[k*100+col]
__global__ void k_gxc(const float* __restrict__ char_emb,
                      const float* __restrict__ cWih_f, const float* __restrict__ cb_f,
                      const float* __restrict__ cWih_b, const float* __restrict__ cb_b,
                      float* __restrict__ gxc){
  int i = blockIdx.x*blockDim.x + threadIdx.x;
  if (i >= 128*2*100) return;
  int col = i % 100; int d = (i/100) & 1; int c = i/200;
  const float* Wih = d ? cWih_b : cWih_f;
  const float* bb  = d ? cb_b  : cb_f;
  float acc = bb[col];
  #pragma unroll
  for (int k=0;k<25;k++) acc += char_emb[c*25+k]*Wih[k*100+col];
  gxc[i] = acc;
}

// ---------------- Kernel 1: char BiLSTM over length-sorted words.
// 4-partial-sum accumulation breaks the 25-deep dependent FMA chain.
__global__ __launch_bounds__(512) void k_char(const int* __restrict__ char_tensor,
   const int* __restrict__ char_lengths, const int* __restrict__ widx,
   const float* __restrict__ cWhh_f, const float* __restrict__ cWhh_b,
   const float* __restrict__ gxc, float* __restrict__ cf){
  __shared__ float h_lds[WPB][28];
  __shared__ float act[WPB][100];
  __shared__ int   chars[WPB][TC];
  __shared__ int   lens[WPB];
  __shared__ int   wids[WPB];
  int tid = threadIdx.x;
  int d  = blockIdx.x & 1;
  int wb = blockIdx.x >> 1;
  int w0 = wb*WPB;
  if (tid < WPB){
    int slot = w0 + tid; if (slot > NWORDS-1) slot = NWORDS-1;
    wids[tid] = widx[slot];
  }
  __syncthreads();
  if (tid < WPB*TC){
    int ww = wids[tid/TC];
    chars[tid/TC][tid%TC] = char_tensor[ww*TC + (tid%TC)];
  }
  if (tid < WPB) lens[tid] = char_lengths[wids[tid]];
  int wsub = tid/100;
  int j    = tid - wsub*100;
  bool gate_thr = tid < WPB*100;
  const float* Wh = d ? cWhh_b : cWhh_f;
  float wcol[25];
  if (gate_thr){
    #pragma unroll
    for (int k=0;k<25;k++) wcol[k] = Wh[k*100 + j];
  }
  if (gate_thr && j < 28) h_lds[wsub][j] = 0.f;
  float c_reg = 0.f, h_last = 0.f;
  __syncthreads();
  int lmax = lens[0];
  #pragma unroll
  for (int q=1;q<WPB;q++) lmax = max(lmax, lens[q]);
  int len = gate_thr ? lens[wsub] : 1;
  bool isg = (j >= 50) && (j < 75);
  float gnext = 0.f;
  if (gate_thr){
    int ci = d ? (len-1) : 0;
    if (ci < 0 || ci >= TC) ci = 0;
    gnext = gxc[(size_t)(chars[wsub][ci]*2+d)*100 + j];
  }
  for (int t=0;t<lmax;t++){
    float gcur = gnext;
    if (gate_thr && t+1 < TC){
      int ci = d ? (len-2-t) : (t+1);
      if (ci < 0 || ci >= TC) ci = 0;
      gnext = gxc[(size_t)(chars[wsub][ci]*2+d)*100 + j];
    }
    if (gate_thr){
      float a0 = gcur, a1 = 0.f, a2 = 0.f, a3 = 0.f;
      const float4* h4 = (const float4*)h_lds[wsub];
      #pragma unroll
      for (int kq=0;kq<6;kq++){
        float4 hq = h4[kq];
        a0 += hq.x*wcol[4*kq];
        a1 += hq.y*wcol[4*kq+1];
        a2 += hq.z*wcol[4*kq+2];
        a3 += hq.w*wcol[4*kq+3];
      }
      a0 += h_lds[wsub][24]*wcol[24];
      float a = (a0+a1)+(a2+a3);
      act[wsub][j] = isg ? tanhf_(a) : sigf(a);
    }
    __syncthreads();
    if (gate_thr && j < 25 && t < len){
      float si = act[wsub][j], sf = act[wsub][25+j], sg = act[wsub][50+j], so = act[wsub][75+j];
      c_reg = sf*c_reg + si*sg;
      float hv = so*tanhf_(c_reg);
      h_lds[wsub][j] = hv;
      h_last = hv;
    }
    __syncthreads();
  }
  if (gate_thr && j < 25){
    int w = wids[wsub];
    cf[(size_t)w*56 + d*28 + j] = h_last;
  }
}

// ---------------- Kernel 3: gx[d][p][400] = wb_d + [word_emb[tok[p]] ++ cf[recover[p]]] @ wWih_d
__global__ __launch_bounds__(256) void k_wih(const int* __restrict__ tok,
    const int* __restrict__ recover,
    const float* __restrict__ word_emb, const float* __restrict__ cf,
    const float* __restrict__ Wf, const float* __restrict__ bf,
    const float* __restrict__ Wb, const float* __restrict__ bbias,
    float* __restrict__ gx){
  __shared__ float As[150][72];
  __shared__ int toks[64], recs[64];
  int tid = threadIdx.x;
  int m0 = (blockIdx.x>>2)*64;
  int nt = blockIdx.x & 3;
  int n0 = nt*256;
  if (tid < 64) toks[tid] = tok[m0 + tid];
  else if (tid < 128) recs[tid-64] = recover[m0 + tid - 64];
  __syncthreads();
  for (int i=tid; i<64*150; i+=256){
    int r = i/150; int k = i - r*150;
    float v;
    if (k < WEd) v = word_emb[(long)toks[r]*WEd + k];
    else {
      int ci = k - WEd;
      int dd = ci/25; int uu = ci - dd*25;
      v = cf[(size_t)recs[r]*56 + dd*28 + uu];
    }
    As[k][r] = v;
  }
  __syncthreads();
  int tn = tid & 31; int tm = tid >> 5;
  int j0 = n0 + tn*8;
  bool colok = j0 < 800;
  int d = (j0 >= 400) ? 1 : 0;
  const float* W = d ? Wb : Wf;
  int jc = j0 - d*400;
  float acc[8][8];
  #pragma unroll
  for (int mi=0;mi<8;mi++)
    #pragma unroll
    for (int ni=0;ni<8;ni++) acc[mi][ni]=0.f;
  if (colok){
    for (int k=0;k<150;k++){
      float4 b0 = *(const float4*)&W[k*400 + jc];
      float4 b1 = *(const float4*)&W[k*400 + jc + 4];
      float4 a0 = *(const float4*)&As[k][tm*8];
      float4 a1 = *(const float4*)&As[k][tm*8+4];
      float av[8] = {a0.x,a0.y,a0.z,a0.w,a1.x,a1.y,a1.z,a1.w};
      float bv[8] = {b0.x,b0.y,b0.z,b0.w,b1.x,b1.y,b1.z,b1.w};
      #pragma unroll
      for (int mi=0;mi<8;mi++)
        #pragma unroll
        for (int ni=0;ni<8;ni++) acc[mi][ni] += av[mi]*bv[ni];
    }
    const float* bptr = d ? bbias : bf;
    float bias[8];
    #pragma unroll
    for (int ni=0;ni<8;ni++) bias[ni] = bptr[jc+ni];
    #pragma unroll
    for (int mi=0;mi<8;mi++){
      int p = m0 + tm*8 + mi;
      float* orow = gx + ((long)d*NWORDS + p)*400 + jc;
      #pragma unroll
      for (int ni=0;ni<8;ni++) orow[ni] = acc[mi][ni] + bias[ni];
    }
  }
}

// ---------------- Kernel 4: word LSTM recurrence (v4 + 4-partial-sum chains).
// The 100-deep dependent FMA chain (400 cyc, strict-FP so the compiler cannot
// reassociate) is split into 4 independent 25-deep chains (~100 cyc).
__global__ __launch_bounds__(448, 2) void k_wlstm(const float* __restrict__ gx,
     const float* __restrict__ Whf, const float* __restrict__ Whb,
     float* __restrict__ hseq){
  __shared__ float wstage[10000];   // 25 rows x 400 cols, 40KB chunk
  __shared__ float h_lds[100];
  __shared__ float act[400];
  int tid = threadIdx.x;
  int s = blockIdx.x & 63; int d = blockIdx.x >> 6;
  const float* Wh = d ? Whb : Whf;
  int j = tid;
  bool colthr = j < 400;
  float wreg[100];
  #pragma unroll
  for (int ch=0; ch<4; ch++){
    for (int i=tid; i<2500; i+=448)
      ((float4*)wstage)[i] = ((const float4*)(Wh + ch*10000))[i];
    __syncthreads();
    if (colthr){
      #pragma unroll
      for (int kk=0;kk<25;kk++) wreg[ch*25+kk] = wstage[kk*400 + j];
    }
    __syncthreads();
  }
  if (tid < 100) h_lds[tid] = 0.f;
  float c_reg = 0.f;
  const float* gxd = gx + ((long)d*NWORDS + (long)s*256)*400;
  bool isg = (j >= 200) && (j < 300);
  __syncthreads();
  float gnext = 0.f;
  if (colthr) gnext = gxd[(d?255:0)*400 + j];
  for (int t=0;t<256;t++){
    float gcur = gnext;
    if (colthr && t+1 < 256){
      int tn = d ? (255-(t+1)) : (t+1);
      gnext = gxd[tn*400 + j];
    }
    if (colthr){
      float a0 = gcur, a1 = 0.f, a2 = 0.f, a3 = 0.f;
      const float4* h4 = (const float4*)h_lds;
      #pragma unroll
      for (int kq=0;kq<25;kq++){
        float4 hq = h4[kq];
        a0 += hq.x*wreg[4*kq];
        a1 += hq.y*wreg[4*kq+1];
        a2 += hq.z*wreg[4*kq+2];
        a3 += hq.w*wreg[4*kq+3];
      }
      float a = (a0+a1)+(a2+a3);
      act[j] = isg ? tanhf_(a) : sigf(a);
    }
    __syncthreads();   // act visible; all h_lds reads of this step done
    if (tid < 100){
      float si = act[tid], sf = act[100+tid], sg = act[200+tid], so = act[300+tid];
      c_reg = sf*c_reg + si*sg;
      float hv = so*tanhf_(c_reg);
      h_lds[tid] = hv;
      int ttc = d ? (255-t) : t;
      hseq[((long)d*NWORDS + s*256 + ttc)*100 + tid] = hv;
    }
    __syncthreads();   // new h visible
  }
}

// ---------------- Kernel 5: emissions em[p][25] = b_tag + concat(h_f,h_b)[p] @ W_tag
__global__ __launch_bounds__(256) void k_em(const float* __restrict__ hseq,
    const float* __restrict__ Wtag, const float* __restrict__ btag,
    float* __restrict__ em){
  __shared__ float hrow[8][200];
  __shared__ float Ws[5000];
  int tid = threadIdx.x;
  for (int i=tid;i<5000;i+=256) Ws[i] = Wtag[i];
  int p0 = blockIdx.x*8;
  for (int i=tid;i<8*200;i+=256){
    int r = i/200; int k = i - r*200;
    int p = p0+r;
    hrow[r][k] = (k<100) ? hseq[(long)p*100+k] : hseq[((long)NWORDS + p)*100 + (k-100)];
  }
  __syncthreads();
  int r = tid>>5; int c = tid&31;
  if (c<25){
    float acc = btag[c];
    for (int k=0;k<200;k++) acc += hrow[r][k]*Ws[k*25+c];
    em[(long)(p0+r)*25 + c] = acc;
  }
}

// ---------------- Kernel 6: CRF per sequence. Lane-per-tag, constant-lane
// readlane broadcasts, baseline-shift logsumexp (exact: base cancels).
__global__ __launch_bounds__(64) void k_crf(const float* __restrict__ em,
    const int* __restrict__ tag, const float* __restrict__ trans,
    const float* __restrict__ start, const float* __restrict__ endv,
    float* __restrict__ part){
  int s = blockIdx.x;
  int lane = threadIdx.x;
  const float* emb = em + (long)s*256*25;
  float tr[25];
  #pragma unroll
  for (int k=0;k<25;k++) tr[k] = (lane<25) ? trans[k*25+lane] : 0.f;
  float alpha = (lane<25) ? (start[lane] + emb[lane]) : 0.f;
  float enext = (lane<25) ? emb[25+lane] : 0.f;
  for (int t=1;t<256;t++){
    float ecur = enext;
    if (t<255 && lane<25) enext = emb[(t+1)*25 + lane];
    float base = RL(alpha, 0);
    float s0=0.f,s1=0.f,s2=0.f,s3=0.f,s4=0.f;
    #pragma unroll
    for (int k=0;k<5;k++) s0 += __expf(RL(alpha,k)    + tr[k]    - base);
    #pragma unroll
    for (int k=0;k<5;k++) s1 += __expf(RL(alpha,5+k)  + tr[5+k]  - base);
    #pragma unroll
    for (int k=0;k<5;k++) s2 += __expf(RL(alpha,10+k) + tr[10+k] - base);
    #pragma unroll
    for (int k=0;k<5;k++) s3 += __expf(RL(alpha,15+k) + tr[15+k] - base);
    #pragma unroll
    for (int k=0;k<5;k++) s4 += __expf(RL(alpha,20+k) + tr[20+k] - base);
    float ssum = ((s0+s1)+(s2+s3))+s4;
    alpha = __logf(ssum) + base + ecur;
  }
  float val = (lane<25) ? (alpha + endv[lane]) : -1e30f;
  float m2 = -1e30f;
  #pragma unroll
  for (int k=0;k<25;k++) m2 = fmaxf(m2, RL(val,k));
  float s2s = 0.f;
  #pragma unroll
  for (int k=0;k<25;k++) s2s += __expf(RL(val,k) - m2);
  float logZ = __logf(s2s) + m2;
  const int* tg = tag + s*256;
  float gp = 0.f;
  for (int t=lane; t<256; t+=64){
    int a = tg[t];
    gp += emb[t*25 + a];
    if (t<255) gp += trans[a*25 + tg[t+1]];
  }
  #pragma unroll
  for (int off=32; off; off>>=1) gp += __shfl_xor(gp, off, 64);
  if (lane==0){
    float gold = gp + start[tg[0]] + endv[tg[255]];
    part[s] = logZ - gold;
  }
}

// ---------------- Kernel 7: final reduce
__global__ __launch_bounds__(64) void k_red(const float* __restrict__ part, float* __restrict__ out){
  float v = part[threadIdx.x];
  #pragma unroll
  for (int off=32; off; off>>=1) v += __shfl_xor(v, off, 64);
  if (threadIdx.x==0) out[0] = v;
}

extern "C" void kernel_launch(void* const* d_in, const int* in_sizes, int n_in,
                              void* d_out, int out_size, void* d_ws, size_t ws_size,
                              hipStream_t stream){
  const int* tok          = (const int*)d_in[0];
  const int* tagp         = (const int*)d_in[1];
  const int* char_tensor  = (const int*)d_in[3];
  const int* char_lengths = (const int*)d_in[4];
  const int* recover      = (const int*)d_in[5];
  const float* word_emb = (const float*)d_in[6];
  const float* char_emb = (const float*)d_in[7];
  const float* cWih_f=(const float*)d_in[8];  const float* cWhh_f=(const float*)d_in[9];  const float* cb_f=(const float*)d_in[10];
  const float* cWih_b=(const float*)d_in[11]; const float* cWhh_b=(const float*)d_in[12]; const float* cb_b=(const float*)d_in[13];
  const float* wWih_f=(const float*)d_in[14]; const float* wWhh_f=(const float*)d_in[15]; const float* wb_f=(const float*)d_in[16];
  const float* wWih_b=(const float*)d_in[17]; const float* wWhh_b=(const float*)d_in[18]; const float* wb_b=(const float*)d_in[19];
  const float* W_tag=(const float*)d_in[20];  const float* b_tag=(const float*)d_in[21];
  const float* trans=(const float*)d_in[22];  const float* startv=(const float*)d_in[23]; const float* endv=(const float*)d_in[24];

  float* ws  = (float*)d_ws;
  float* gxc = ws;                 // [0, 25600)
  float* cf  = ws + 25600;         // [25600, 943104)
  float* gx  = ws + 943104;        // [943104, 14050304)
  float* hseq= ws + 14050304;      // [14050304, 17327104)
  float* em  = ws;                 // overlays gxc+cf (dead after k_wih), 409600
  float* part= ws + 17327104;      // 64
  int*   meta= (int*)(ws + 17327168);  // hist[16]+cursor[16]+pad
  int*   widx= meta + 64;              // 16384 ints (high water ~69.4 MB)
  float* out = (float*)d_out;

  k_zero   <<<1,   64,  0, stream>>>(meta);
  k_gxc    <<<100, 256, 0, stream>>>(char_emb, cWih_f, cb_f, cWih_b, cb_b, gxc);
  k_hist   <<<64,  256, 0, stream>>>(char_lengths, meta);
  k_scan   <<<1,   64,  0, stream>>>(meta, meta+16);
  k_scatter<<<64,  256, 0, stream>>>(char_lengths, meta+16, widx);
  k_char   <<<6554,512, 0, stream>>>(char_tensor, char_lengths, widx, cWhh_f, cWhh_b, gxc, cf);
  k_wih    <<<1024,256, 0, stream>>>(tok, recover, word_emb, cf, wWih_f, wb_f, wWih_b, wb_b, gx);
  k_wlstm  <<<128, 448, 0, stream>>>(gx, wWhh_f, wWhh_b, hseq);
  k_em     <<<2048,256, 0, stream>>>(hseq, W_tag, b_tag, em);
  k_crf    <<<64,  64,  0, stream>>>(em, tagp, trans, startv, endv, part);
  k_red    <<<1,   64,  0, stream>>>(part, out);
}

// Round 17
// 524.700 us; speedup vs baseline: 1.5966x; 1.0219x over previous
//
#include <hip/hip_runtime.h>
#include <hip/hip_bf16.h>

// Problem constants
#define NB 64
#define NT 256
#define TC 16
#define NL 25
#define NWORDS 16384   // NB*NT
#define DWd 150        // word-LSTM input dim
#define WEd 100
#define WPB 5          // words per k_char block

__device__ __forceinline__ float sigf(float x){ return __fdividef(1.f, 1.f + __expf(-x)); }
__device__ __forceinline__ float tanhf_(float x){
    float ax = fabsf(x);
    float e = __expf(-2.f*ax);                 // e in (0,1], overflow-safe
    float r = (1.f - e) * __fdividef(1.f, 1.f + e);
    return copysignf(r, x);
}
__device__ __forceinline__ float RL(float v, int k){
    return __int_as_float(__builtin_amdgcn_readlane(__float_as_int(v), k));
}

// ---------------- Sort kernels: bucket words by char length (16 buckets).
__global__ void k_zero(int* __restrict__ meta){
  if (threadIdx.x < 34) meta[threadIdx.x] = 0;
}
__global__ __launch_bounds__(256) void k_hist(const int* __restrict__ char_lengths,
                                              int* __restrict__ hist){
  __shared__ int lh[16];
  int tid = threadIdx.x;
  if (tid < 16) lh[tid] = 0;
  __syncthreads();
  int w = blockIdx.x*256 + tid;
  atomicAdd(&lh[char_lengths[w]-1], 1);
  __syncthreads();
  if (tid < 16) atomicAdd(&hist[tid], lh[tid]);
}
__global__ void k_scan(const int* __restrict__ hist, int* __restrict__ cursor){
  if (threadIdx.x == 0){
    int acc = 0;
    for (int i=0;i<16;i++){ cursor[i] = acc; acc += hist[i]; }
  }
}
__global__ __launch_bounds__(256) void k_scatter(const int* __restrict__ char_lengths,
                                                 int* __restrict__ cursor,
                                                 int* __restrict__ widx){
  __shared__ int lh[16], lbase[16];
  int tid = threadIdx.x;
  if (tid < 16) lh[tid] = 0;
  __syncthreads();
  int w = blockIdx.x*256 + tid;
  int len = char_lengths[w]-1;
  int lrank = atomicAdd(&lh[len], 1);
  __syncthreads();
  if (tid < 16) lbase[tid] = atomicAdd(&cursor[tid], lh[tid]);
  __syncthreads();
  widx[lbase[len] + lrank] = w;
}

// ---------------- Kernel 0: gxc[(c,d)][col] = cb_d[col] + sum_k char_emb[c][k]*cWih_d[k*100+col]
__global__ void k_gxc(const float* __restrict__ char_emb,
                      const float* __restrict__ cWih_f, const float* __restrict__ cb_f,
                      const float* __restrict__ cWih_b, const float* __restrict__ cb_b,
                      float* __restrict__ gxc){
  int i = blockIdx.x*blockDim.x + threadIdx.x;
  if (i >= 128*2*100) return;
  int col = i % 100; int d = (i/100) & 1; int c = i/200;
  const float* Wih = d ? cWih_b : cWih_f;
  const float* bb  = d ? cb_b  : cb_f;
  float acc = bb[col];
  #pragma unroll
  for (int k=0;k<25;k++) acc += char_emb[c*25+k]*Wih[k*100+col];
  gxc[i] = acc;
}

// ---------------- Kernel 1: char BiLSTM over length-sorted words.
__global__ __launch_bounds__(512) void k_char(const int* __restrict__ char_tensor,
   const int* __restrict__ char_lengths, const int* __restrict__ widx,
   const float* __restrict__ cWhh_f, const float* __restrict__ cWhh_b,
   const float* __restrict__ gxc, float* __restrict__ cf){
  __shared__ float h_lds[WPB][28];
  __shared__ float act[WPB][100];
  __shared__ int   chars[WPB][TC];
  __shared__ int   lens[WPB];
  __shared__ int   wids[WPB];
  int tid = threadIdx.x;
  int d  = blockIdx.x & 1;
  int wb = blockIdx.x >> 1;
  int w0 = wb*WPB;
  if (tid < WPB){
    int slot = w0 + tid; if (slot > NWORDS-1) slot = NWORDS-1;
    wids[tid] = widx[slot];
  }
  __syncthreads();
  if (tid < WPB*TC){
    int ww = wids[tid/TC];
    chars[tid/TC][tid%TC] = char_tensor[ww*TC + (tid%TC)];
  }
  if (tid < WPB) lens[tid] = char_lengths[wids[tid]];
  int wsub = tid/100;
  int j    = tid - wsub*100;
  bool gate_thr = tid < WPB*100;
  const float* Wh = d ? cWhh_b : cWhh_f;
  float wcol[25];
  if (gate_thr){
    #pragma unroll
    for (int k=0;k<25;k++) wcol[k] = Wh[k*100 + j];
  }
  if (gate_thr && j < 28) h_lds[wsub][j] = 0.f;
  float c_reg = 0.f, h_last = 0.f;
  __syncthreads();
  int lmax = lens[0];
  #pragma unroll
  for (int q=1;q<WPB;q++) lmax = max(lmax, lens[q]);
  int len = gate_thr ? lens[wsub] : 1;
  bool isg = (j >= 50) && (j < 75);
  float gnext = 0.f;
  if (gate_thr){
    int ci = d ? (len-1) : 0;
    if (ci < 0 || ci >= TC) ci = 0;
    gnext = gxc[(size_t)(chars[wsub][ci]*2+d)*100 + j];
  }
  for (int t=0;t<lmax;t++){
    float gcur = gnext;
    if (gate_thr && t+1 < TC){
      int ci = d ? (len-2-t) : (t+1);
      if (ci < 0 || ci >= TC) ci = 0;
      gnext = gxc[(size_t)(chars[wsub][ci]*2+d)*100 + j];
    }
    if (gate_thr){
      float a0 = gcur, a1 = 0.f, a2 = 0.f, a3 = 0.f;
      const float4* h4 = (const float4*)h_lds[wsub];
      #pragma unroll
      for (int kq=0;kq<6;kq++){
        float4 hq = h4[kq];
        a0 += hq.x*wcol[4*kq];
        a1 += hq.y*wcol[4*kq+1];
        a2 += hq.z*wcol[4*kq+2];
        a3 += hq.w*wcol[4*kq+3];
      }
      a0 += h_lds[wsub][24]*wcol[24];
      float a = (a0+a1)+(a2+a3);
      act[wsub][j] = isg ? tanhf_(a) : sigf(a);
    }
    __syncthreads();
    if (gate_thr && j < 25 && t < len){
      float si = act[wsub][j], sf = act[wsub][25+j], sg = act[wsub][50+j], so = act[wsub][75+j];
      c_reg = sf*c_reg + si*sg;
      float hv = so*tanhf_(c_reg);
      h_lds[wsub][j] = hv;
      h_last = hv;
    }
    __syncthreads();
  }
  if (gate_thr && j < 25){
    int w = wids[wsub];
    cf[(size_t)w*56 + d*28 + j] = h_last;
  }
}

// ---------------- Kernel 3: gx[d][p][400] = wb_d + [word_emb[tok[p]] ++ cf[recover[p]]] @ wWih_d
__global__ __launch_bounds__(256) void k_wih(const int* __restrict__ tok,
    const int* __restrict__ recover,
    const float* __restrict__ word_emb, const float* __restrict__ cf,
    const float* __restrict__ Wf, const float* __restrict__ bf,
    const float* __restrict__ Wb, const float* __restrict__ bbias,
    float* __restrict__ gx){
  __shared__ float As[150][72];
  __shared__ int toks[64], recs[64];
  int tid = threadIdx.x;
  int m0 = (blockIdx.x>>2)*64;
  int nt = blockIdx.x & 3;
  int n0 = nt*256;
  if (tid < 64) toks[tid] = tok[m0 + tid];
  else if (tid < 128) recs[tid-64] = recover[m0 + tid - 64];
  __syncthreads();
  for (int i=tid; i<64*150; i+=256){
    int r = i/150; int k = i - r*150;
    float v;
    if (k < WEd) v = word_emb[(long)toks[r]*WEd + k];
    else {
      int ci = k - WEd;
      int dd = ci/25; int uu = ci - dd*25;
      v = cf[(size_t)recs[r]*56 + dd*28 + uu];
    }
    As[k][r] = v;
  }
  __syncthreads();
  int tn = tid & 31; int tm = tid >> 5;
  int j0 = n0 + tn*8;
  bool colok = j0 < 800;
  int d = (j0 >= 400) ? 1 : 0;
  const float* W = d ? Wb : Wf;
  int jc = j0 - d*400;
  float acc[8][8];
  #pragma unroll
  for (int mi=0;mi<8;mi++)
    #pragma unroll
    for (int ni=0;ni<8;ni++) acc[mi][ni]=0.f;
  if (colok){
    for (int k=0;k<150;k++){
      float4 b0 = *(const float4*)&W[k*400 + jc];
      float4 b1 = *(const float4*)&W[k*400 + jc + 4];
      float4 a0 = *(const float4*)&As[k][tm*8];
      float4 a1 = *(const float4*)&As[k][tm*8+4];
      float av[8] = {a0.x,a0.y,a0.z,a0.w,a1.x,a1.y,a1.z,a1.w};
      float bv[8] = {b0.x,b0.y,b0.z,b0.w,b1.x,b1.y,b1.z,b1.w};
      #pragma unroll
      for (int mi=0;mi<8;mi++)
        #pragma unroll
        for (int ni=0;ni<8;ni++) acc[mi][ni] += av[mi]*bv[ni];
    }
    const float* bptr = d ? bbias : bf;
    float bias[8];
    #pragma unroll
    for (int ni=0;ni<8;ni++) bias[ni] = bptr[jc+ni];
    #pragma unroll
    for (int mi=0;mi<8;mi++){
      int p = m0 + tm*8 + mi;
      float* orow = gx + ((long)d*NWORDS + p)*400 + jc;
      #pragma unroll
      for (int ni=0;ni<8;ni++) orow[ni] = acc[mi][ni] + bias[ni];
    }
  }
}

// ---------------- Kernel 4: word LSTM recurrence (v4 + lgkm-only barriers + 2-deep gx prefetch).
// Block-internal comms are LDS-only (hseq never re-read, gx read-only), so raw
// s_barrier preceded by lgkmcnt(0) ONLY is safe — gx prefetch loads and hseq
// stores stay in flight across barriers (T4), removing the per-step vmcnt(0)
// drain that __syncthreads() forces. 2-deep prefetch makes the consumed load
// >=2 steps (~1400cyc) old.
__global__ __launch_bounds__(448, 2) void k_wlstm(const float* __restrict__ gx,
     const float* __restrict__ Whf, const float* __restrict__ Whb,
     float* __restrict__ hseq){
  __shared__ float wstage[10000];   // 25 rows x 400 cols, 40KB chunk
  __shared__ float h_lds[100];
  __shared__ float act[400];
  int tid = threadIdx.x;
  int s = blockIdx.x & 63; int d = blockIdx.x >> 6;
  const float* Wh = d ? Whb : Whf;
  int j = tid;
  bool colthr = j < 400;
  float wreg[100];
  #pragma unroll
  for (int ch=0; ch<4; ch++){
    for (int i=tid; i<2500; i+=448)
      ((float4*)wstage)[i] = ((const float4*)(Wh + ch*10000))[i];
    __syncthreads();
    if (colthr){
      #pragma unroll
      for (int kk=0;kk<25;kk++) wreg[ch*25+kk] = wstage[kk*400 + j];
    }
    __syncthreads();
  }
  if (tid < 100) h_lds[tid] = 0.f;
  float c_reg = 0.f;
  const float* gxd = gx + ((long)d*NWORDS + (long)s*256)*400;
  bool isg = (j >= 200) && (j < 300);
  __syncthreads();
  float gnext = 0.f, gnext2 = 0.f;
  if (colthr){
    gnext  = gxd[(d?255:0)*400 + j];
    gnext2 = gxd[(d?254:1)*400 + j];
  }
  for (int t=0;t<256;t++){
    float gcur = gnext;
    gnext = gnext2;
    if (colthr && t+2 < 256){
      int tn = d ? (255-(t+2)) : (t+2);
      gnext2 = gxd[tn*400 + j];
    }
    if (colthr){
      float a0 = gcur, a1 = 0.f, a2 = 0.f, a3 = 0.f;
      const float4* h4 = (const float4*)h_lds;
      #pragma unroll
      for (int kq=0;kq<25;kq++){
        float4 hq = h4[kq];
        a0 += hq.x*wreg[4*kq];
        a1 += hq.y*wreg[4*kq+1];
        a2 += hq.z*wreg[4*kq+2];
        a3 += hq.w*wreg[4*kq+3];
      }
      float a = (a0+a1)+(a2+a3);
      act[j] = isg ? tanhf_(a) : sigf(a);
    }
    asm volatile("s_waitcnt lgkmcnt(0)" ::: "memory");
    __builtin_amdgcn_s_barrier();      // act visible; h_lds reads done
    if (tid < 100){
      float si = act[tid], sf = act[100+tid], sg = act[200+tid], so = act[300+tid];
      c_reg = sf*c_reg + si*sg;
      float hv = so*tanhf_(c_reg);
      h_lds[tid] = hv;
      int ttc = d ? (255-t) : t;
      hseq[((long)d*NWORDS + s*256 + ttc)*100 + tid] = hv;
    }
    asm volatile("s_waitcnt lgkmcnt(0)" ::: "memory");
    __builtin_amdgcn_s_barrier();      // new h visible
  }
}

// ---------------- Kernel 5: emissions em[p][25] = b_tag + concat(h_f,h_b)[p] @ W_tag
__global__ __launch_bounds__(256) void k_em(const float* __restrict__ hseq,
    const float* __restrict__ Wtag, const float* __restrict__ btag,
    float* __restrict__ em){
  __shared__ float hrow[8][200];
  __shared__ float Ws[5000];
  int tid = threadIdx.x;
  for (int i=tid;i<5000;i+=256) Ws[i] = Wtag[i];
  int p0 = blockIdx.x*8;
  for (int i=tid;i<8*200;i+=256){
    int r = i/200; int k = i - r*200;
    int p = p0+r;
    hrow[r][k] = (k<100) ? hseq[(long)p*100+k] : hseq[((long)NWORDS + p)*100 + (k-100)];
  }
  __syncthreads();
  int r = tid>>5; int c = tid&31;
  if (c<25){
    float acc = btag[c];
    for (int k=0;k<200;k++) acc += hrow[r][k]*Ws[k*25+c];
    em[(long)(p0+r)*25 + c] = acc;
  }
}

// ---------------- Kernel 6: CRF per sequence. Per step: ONE exp per lane
// (exp(alpha_k - base), distributed) + 25 readlane-FMAs against precomputed
// etr[k]=exp(trans[k][lane]) — exact same logsumexp (products of exps), 25x
// fewer transcendentals on the serial path.
__global__ __launch_bounds__(64) void k_crf(const float* __restrict__ em,
    const int* __restrict__ tag, const float* __restrict__ trans,
    const float* __restrict__ start, const float* __restrict__ endv,
    float* __restrict__ part){
  int s = blockIdx.x;
  int lane = threadIdx.x;
  const float* emb = em + (long)s*256*25;
  float etr[25];
  #pragma unroll
  for (int k=0;k<25;k++) etr[k] = (lane<25) ? __expf(trans[k*25+lane]) : 0.f;
  float alpha = (lane<25) ? (start[lane] + emb[lane]) : 0.f;
  float enext = (lane<25) ? emb[25+lane] : 0.f;
  for (int t=1;t<256;t++){
    float ecur = enext;
    if (t<255 && lane<25) enext = emb[(t+1)*25 + lane];
    float base = RL(alpha, 0);
    float e = __expf(alpha - base);      // valid on lanes 0..24 (those are read)
    float s0=0.f,s1=0.f,s2=0.f,s3=0.f,s4=0.f;
    #pragma unroll
    for (int k=0;k<5;k++) s0 += RL(e,k)    * etr[k];
    #pragma unroll
    for (int k=0;k<5;k++) s1 += RL(e,5+k)  * etr[5+k];
    #pragma unroll
    for (int k=0;k<5;k++) s2 += RL(e,10+k) * etr[10+k];
    #pragma unroll
    for (int k=0;k<5;k++) s3 += RL(e,15+k) * etr[15+k];
    #pragma unroll
    for (int k=0;k<5;k++) s4 += RL(e,20+k) * etr[20+k];
    float ssum = ((s0+s1)+(s2+s3))+s4;
    alpha = __logf(ssum) + base + ecur;
  }
  float val = (lane<25) ? (alpha + endv[lane]) : -1e30f;
  float m2 = -1e30f;
  #pragma unroll
  for (int k=0;k<25;k++) m2 = fmaxf(m2, RL(val,k));
  float s2s = 0.f;
  #pragma unroll
  for (int k=0;k<25;k++) s2s += __expf(RL(val,k) - m2);
  float logZ = __logf(s2s) + m2;
  const int* tg = tag + s*256;
  float gp = 0.f;
  for (int t=lane; t<256; t+=64){
    int a = tg[t];
    gp += emb[t*25 + a];
    if (t<255) gp += trans[a*25 + tg[t+1]];
  }
  #pragma unroll
  for (int off=32; off; off>>=1) gp += __shfl_xor(gp, off, 64);
  if (lane==0){
    float gold = gp + start[tg[0]] + endv[tg[255]];
    part[s] = logZ - gold;
  }
}

// ---------------- Kernel 7: final reduce
__global__ __launch_bounds__(64) void k_red(const float* __restrict__ part, float* __restrict__ out){
  float v = part[threadIdx.x];
  #pragma unroll
  for (int off=32; off; off>>=1) v += __shfl_xor(v, off, 64);
  if (threadIdx.x==0) out[0] = v;
}

extern "C" void kernel_launch(void* const* d_in, const int* in_sizes, int n_in,
                              void* d_out, int out_size, void* d_ws, size_t ws_size,
                              hipStream_t stream){
  const int* tok          = (const int*)d_in[0];
  const int* tagp         = (const int*)d_in[1];
  const int* char_tensor  = (const int*)d_in[3];
  const int* char_lengths = (const int*)d_in[4];
  const int* recover      = (const int*)d_in[5];
  const float* word_emb = (const float*)d_in[6];
  const float* char_emb = (const float*)d_in[7];
  const float* cWih_f=(const float*)d_in[8];  const float* cWhh_f=(const float*)d_in[9];  const float* cb_f=(const float*)d_in[10];
  const float* cWih_b=(const float*)d_in[11]; const float* cWhh_b=(const float*)d_in[12]; const float* cb_b=(const float*)d_in[13];
  const float* wWih_f=(const float*)d_in[14]; const float* wWhh_f=(const float*)d_in[15]; const float* wb_f=(const float*)d_in[16];
  const float* wWih_b=(const float*)d_in[17]; const float* wWhh_b=(const float*)d_in[18]; const float* wb_b=(const float*)d_in[19];
  const float* W_tag=(const float*)d_in[20];  const float* b_tag=(const float*)d_in[21];
  const float* trans=(const float*)d_in[22];  const float* startv=(const float*)d_in[23]; const float* endv=(const float*)d_in[24];

  float* ws  = (float*)d_ws;
  float* gxc = ws;                 // [0, 25600)
  float* cf  = ws + 25600;         // [25600, 943104)
  float* gx  = ws + 943104;        // [943104, 14050304)
  float* hseq= ws + 14050304;      // [14050304, 17327104)
  float* em  = ws;                 // overlays gxc+cf (dead after k_wih), 409600
  float* part= ws + 17327104;      // 64
  int*   meta= (int*)(ws + 17327168);  // hist[16]+cursor[16]+pad
  int*   widx= meta + 64;              // 16384 ints (high water ~69.4 MB)
  float* out = (float*)d_out;

  k_zero   <<<1,   64,  0, stream>>>(meta);
  k_gxc    <<<100, 256, 0, stream>>>(char_emb, cWih_f, cb_f, cWih_b, cb_b, gxc);
  k_hist   <<<64,  256, 0, stream>>>(char_lengths, meta);
  k_scan   <<<1,   64,  0, stream>>>(meta, meta+16);
  k_scatter<<<64,  256, 0, stream>>>(char_lengths, meta+16, widx);
  k_char   <<<6554,512, 0, stream>>>(char_tensor, char_lengths, widx, cWhh_f, cWhh_b, gxc, cf);
  k_wih    <<<1024,256, 0, stream>>>(tok, recover, word_emb, cf, wWih_f, wb_f, wWih_b, wb_b, gx);
  k_wlstm  <<<128, 448, 0, stream>>>(gx, wWhh_f, wWhh_b, hseq);
  k_em     <<<2048,256, 0, stream>>>(hseq, W_tag, b_tag, em);
  k_crf    <<<64,  64,  0, stream>>>(em, tagp, trans, startv, endv, part);
  k_red    <<<1,   64,  0, stream>>>(part, out);
}

// Round 18
// 521.707 us; speedup vs baseline: 1.6058x; 1.0057x over previous
//
#include <hip/hip_runtime.h>
#include <hip/hip_bf16.h>

// Problem constants
#define NB 64
#define NT 256
#define TC 16
#define NL 25
#define NWORDS 16384   // NB*NT
#define DWd 150        // word-LSTM input dim
#define WEd 100
#define WPB 5          // words per k_char block

__device__ __forceinline__ float sigf(float x){ return __fdividef(1.f, 1.f + __expf(-x)); }
__device__ __forceinline__ float tanhf_(float x){
    float ax = fabsf(x);
    float e = __expf(-2.f*ax);                 // e in (0,1], overflow-safe
    float r = (1.f - e) * __fdividef(1.f, 1.f + e);
    return copysignf(r, x);
}
__device__ __forceinline__ float RL(float v, int k){
    return __int_as_float(__builtin_amdgcn_readlane(__float_as_int(v), k));
}

// ---------------- Sort kernels: bucket words by char length (16 buckets).
__global__ void k_zero(int* __restrict__ meta){
  if (threadIdx.x < 34) meta[threadIdx.x] = 0;
}
__global__ __launch_bounds__(256) void k_hist(const int* __restrict__ char_lengths,
                                              int* __restrict__ hist){
  __shared__ int lh[16];
  int tid = threadIdx.x;
  if (tid < 16) lh[tid] = 0;
  __syncthreads();
  int w = blockIdx.x*256 + tid;
  atomicAdd(&lh[char_lengths[w]-1], 1);
  __syncthreads();
  if (tid < 16) atomicAdd(&hist[tid], lh[tid]);
}
__global__ void k_scan(const int* __restrict__ hist, int* __restrict__ cursor){
  if (threadIdx.x == 0){
    int acc = 0;
    for (int i=0;i<16;i++){ cursor[i] = acc; acc += hist[i]; }
  }
}
__global__ __launch_bounds__(256) void k_scatter(const int* __restrict__ char_lengths,
                                                 int* __restrict__ cursor,
                                                 int* __restrict__ widx){
  __shared__ int lh[16], lbase[16];
  int tid = threadIdx.x;
  if (tid < 16) lh[tid] = 0;
  __syncthreads();
  int w = blockIdx.x*256 + tid;
  int len = char_lengths[w]-1;
  int lrank = atomicAdd(&lh[len], 1);
  __syncthreads();
  if (tid < 16) lbase[tid] = atomicAdd(&cursor[tid], lh[tid]);
  __syncthreads();
  widx[lbase[len] + lrank] = w;
}

// ---------------- Kernel 0: gxc[(c,d)][col] = cb_d[col] + sum_k char_emb[c][k]*cWih_d[k*100+col]
__global__ void k_gxc(const float* __restrict__ char_emb,
                      const float* __restrict__ cWih_f, const float* __restrict__ cb_f,
                      const float* __restrict__ cWih_b, const float* __restrict__ cb_b,
                      float* __restrict__ gxc){
  int i = blockIdx.x*blockDim.x + threadIdx.x;
  if (i >= 128*2*100) return;
  int col = i % 100; int d = (i/100) & 1; int c = i/200;
  const float* Wih = d ? cWih_b : cWih_f;
  const float* bb  = d ? cb_b  : cb_f;
  float acc = bb[col];
  #pragma unroll
  for (int k=0;k<25;k++) acc += char_emb[c*25+k]*Wih[k*100+col];
  gxc[i] = acc;
}

// ---------------- Kernel 1: char BiLSTM v4 over length-sorted words.
// thread = (word, unit, gate): the 4 gates of a unit sit in 4 ADJACENT lanes ->
// act exchange via 3 shfl_xor (DPP), no act LDS, ONE barrier/step. h parity-
// buffered; always-write with h_last carry keeps predicated tail steps exact.
__global__ __launch_bounds__(512) void k_char(const int* __restrict__ char_tensor,
   const int* __restrict__ char_lengths, const int* __restrict__ widx,
   const float* __restrict__ cWhh_f, const float* __restrict__ cWhh_b,
   const float* __restrict__ gxc, float* __restrict__ cf){
  __shared__ float h_lds[2][WPB][28];
  __shared__ int   chars[WPB][TC];
  __shared__ int   lens[WPB];
  __shared__ int   wids[WPB];
  int tid = threadIdx.x;
  int d  = blockIdx.x & 1;
  int wb = blockIdx.x >> 1;
  int w0 = wb*WPB;
  if (tid < WPB){
    int slot = w0 + tid; if (slot > NWORDS-1) slot = NWORDS-1;
    wids[tid] = widx[slot];
  }
  __syncthreads();
  if (tid < WPB*TC){
    int ww = wids[tid/TC];
    chars[tid/TC][tid%TC] = char_tensor[ww*TC + (tid%TC)];
  }
  if (tid < WPB) lens[tid] = char_lengths[wids[tid]];
  if (tid < 2*WPB*28){
    int p = tid/(WPB*28); int rr = tid - p*WPB*28;
    h_lds[p][rr/28][rr%28] = 0.f;
  }
  int wsub = tid/100;
  int r    = tid - wsub*100;   // 0..99
  int u    = r >> 2;           // unit 0..24
  int gid  = r & 3;            // gate: 0=i 1=f 2=g 3=o
  bool gate_thr = tid < WPB*100;
  int col = gid*25 + u;
  const float* Wh = d ? cWhh_b : cWhh_f;
  float wcol[25];
  if (gate_thr){
    #pragma unroll
    for (int k=0;k<25;k++) wcol[k] = Wh[k*100 + col];
  }
  float c_reg = 0.f, h_last = 0.f;
  __syncthreads();
  int lmax = lens[0];
  #pragma unroll
  for (int q=1;q<WPB;q++) lmax = max(lmax, lens[q]);
  int len = gate_thr ? lens[wsub] : 1;
  bool isg = (gid == 2);
  float gnext = 0.f;
  if (gate_thr){
    int ci = d ? (len-1) : 0;
    if (ci < 0 || ci >= TC) ci = 0;
    gnext = gxc[(size_t)(chars[wsub][ci]*2+d)*100 + col];
  }
  for (int t=0;t<lmax;t++){
    float gcur = gnext;
    if (gate_thr && t+1 < TC){
      int ci = d ? (len-2-t) : (t+1);
      if (ci < 0 || ci >= TC) ci = 0;
      gnext = gxc[(size_t)(chars[wsub][ci]*2+d)*100 + col];
    }
    float x = 0.f;
    if (gate_thr){
      float a0 = gcur, a1 = 0.f, a2 = 0.f, a3 = 0.f;
      const float4* h4 = (const float4*)h_lds[t&1][wsub];
      #pragma unroll
      for (int kq=0;kq<6;kq++){
        float4 hq = h4[kq];
        a0 += hq.x*wcol[4*kq];
        a1 += hq.y*wcol[4*kq+1];
        a2 += hq.z*wcol[4*kq+2];
        a3 += hq.w*wcol[4*kq+3];
      }
      a0 += h_lds[t&1][wsub][24]*wcol[24];
      float a = (a0+a1)+(a2+a3);
      x = isg ? tanhf_(a) : sigf(a);
    }
    float A = __shfl_xor(x, 1, 64);   // gate gid^1
    float B = __shfl_xor(x, 2, 64);   // gate gid^2
    float C = __shfl_xor(B, 1, 64);   // gate gid^3
    if (gate_thr && gid == 0){
      // x=i, A=f, B=g, C=o (already activated)
      float hv;
      if (t < len){
        c_reg = A*c_reg + x*B;
        hv = C*tanhf_(c_reg);
        h_last = hv;
      } else hv = h_last;
      h_lds[(t+1)&1][wsub][u] = hv;
    }
    __syncthreads();   // new h visible (parity write, no read/write race)
  }
  if (gate_thr && gid == 0){
    int w = wids[wsub];
    cf[(size_t)w*56 + d*28 + u] = h_last;
  }
}

// ---------------- Kernel 3: gx[d][p][400] = wb_d + [word_emb[tok[p]] ++ cf[recover[p]]] @ wWih_d
__global__ __launch_bounds__(256) void k_wih(const int* __restrict__ tok,
    const int* __restrict__ recover,
    const float* __restrict__ word_emb, const float* __restrict__ cf,
    const float* __restrict__ Wf, const float* __restrict__ bf,
    const float* __restrict__ Wb, const float* __restrict__ bbias,
    float* __restrict__ gx){
  __shared__ float As[150][72];
  __shared__ int toks[64], recs[64];
  int tid = threadIdx.x;
  int m0 = (blockIdx.x>>2)*64;
  int nt = blockIdx.x & 3;
  int n0 = nt*256;
  if (tid < 64) toks[tid] = tok[m0 + tid];
  else if (tid < 128) recs[tid-64] = recover[m0 + tid - 64];
  __syncthreads();
  for (int i=tid; i<64*150; i+=256){
    int r = i/150; int k = i - r*150;
    float v;
    if (k < WEd) v = word_emb[(long)toks[r]*WEd + k];
    else {
      int ci = k - WEd;
      int dd = ci/25; int uu = ci - dd*25;
      v = cf[(size_t)recs[r]*56 + dd*28 + uu];
    }
    As[k][r] = v;
  }
  __syncthreads();
  int tn = tid & 31; int tm = tid >> 5;
  int j0 = n0 + tn*8;
  bool colok = j0 < 800;
  int d = (j0 >= 400) ? 1 : 0;
  const float* W = d ? Wb : Wf;
  int jc = j0 - d*400;
  float acc[8][8];
  #pragma unroll
  for (int mi=0;mi<8;mi++)
    #pragma unroll
    for (int ni=0;ni<8;ni++) acc[mi][ni]=0.f;
  if (colok){
    for (int k=0;k<150;k++){
      float4 b0 = *(const float4*)&W[k*400 + jc];
      float4 b1 = *(const float4*)&W[k*400 + jc + 4];
      float4 a0 = *(const float4*)&As[k][tm*8];
      float4 a1 = *(const float4*)&As[k][tm*8+4];
      float av[8] = {a0.x,a0.y,a0.z,a0.w,a1.x,a1.y,a1.z,a1.w};
      float bv[8] = {b0.x,b0.y,b0.z,b0.w,b1.x,b1.y,b1.z,b1.w};
      #pragma unroll
      for (int mi=0;mi<8;mi++)
        #pragma unroll
        for (int ni=0;ni<8;ni++) acc[mi][ni] += av[mi]*bv[ni];
    }
    const float* bptr = d ? bbias : bf;
    float bias[8];
    #pragma unroll
    for (int ni=0;ni<8;ni++) bias[ni] = bptr[jc+ni];
    #pragma unroll
    for (int mi=0;mi<8;mi++){
      int p = m0 + tm*8 + mi;
      float* orow = gx + ((long)d*NWORDS + p)*400 + jc;
      #pragma unroll
      for (int ni=0;ni<8;ni++) orow[ni] = acc[mi][ni] + bias[ni];
    }
  }
}

// ---------------- Kernel 4: word LSTM recurrence (R16 exact: v4 + 4-partial-sum chains).
__global__ __launch_bounds__(448, 2) void k_wlstm(const float* __restrict__ gx,
     const float* __restrict__ Whf, const float* __restrict__ Whb,
     float* __restrict__ hseq){
  __shared__ float wstage[10000];   // 25 rows x 400 cols, 40KB chunk
  __shared__ float h_lds[100];
  __shared__ float act[400];
  int tid = threadIdx.x;
  int s = blockIdx.x & 63; int d = blockIdx.x >> 6;
  const float* Wh = d ? Whb : Whf;
  int j = tid;
  bool colthr = j < 400;
  float wreg[100];
  #pragma unroll
  for (int ch=0; ch<4; ch++){
    for (int i=tid; i<2500; i+=448)
      ((float4*)wstage)[i] = ((const float4*)(Wh + ch*10000))[i];
    __syncthreads();
    if (colthr){
      #pragma unroll
      for (int kk=0;kk<25;kk++) wreg[ch*25+kk] = wstage[kk*400 + j];
    }
    __syncthreads();
  }
  if (tid < 100) h_lds[tid] = 0.f;
  float c_reg = 0.f;
  const float* gxd = gx + ((long)d*NWORDS + (long)s*256)*400;
  bool isg = (j >= 200) && (j < 300);
  __syncthreads();
  float gnext = 0.f;
  if (colthr) gnext = gxd[(d?255:0)*400 + j];
  for (int t=0;t<256;t++){
    float gcur = gnext;
    if (colthr && t+1 < 256){
      int tn = d ? (255-(t+1)) : (t+1);
      gnext = gxd[tn*400 + j];
    }
    if (colthr){
      float a0 = gcur, a1 = 0.f, a2 = 0.f, a3 = 0.f;
      const float4* h4 = (const float4*)h_lds;
      #pragma unroll
      for (int kq=0;kq<25;kq++){
        float4 hq = h4[kq];
        a0 += hq.x*wreg[4*kq];
        a1 += hq.y*wreg[4*kq+1];
        a2 += hq.z*wreg[4*kq+2];
        a3 += hq.w*wreg[4*kq+3];
      }
      float a = (a0+a1)+(a2+a3);
      act[j] = isg ? tanhf_(a) : sigf(a);
    }
    __syncthreads();   // act visible; all h_lds reads of this step done
    if (tid < 100){
      float si = act[tid], sf = act[100+tid], sg = act[200+tid], so = act[300+tid];
      c_reg = sf*c_reg + si*sg;
      float hv = so*tanhf_(c_reg);
      h_lds[tid] = hv;
      int ttc = d ? (255-t) : t;
      hseq[((long)d*NWORDS + s*256 + ttc)*100 + tid] = hv;
    }
    __syncthreads();   // new h visible
  }
}

// ---------------- Kernel 5: emissions em[p][25] = b_tag + concat(h_f,h_b)[p] @ W_tag
// Ws transposed in LDS -> float4 reads on both operands (4x fewer LDS insts).
__global__ __launch_bounds__(256) void k_em(const float* __restrict__ hseq,
    const float* __restrict__ Wtag, const float* __restrict__ btag,
    float* __restrict__ em){
  __shared__ float hrow[8][200];
  __shared__ float WsT[25][204];
  int tid = threadIdx.x;
  for (int i=tid;i<5000;i+=256){
    int c = i/200; int k = i - c*200;
    WsT[c][k] = Wtag[k*25 + c];
  }
  int p0 = blockIdx.x*8;
  for (int i=tid;i<8*200;i+=256){
    int r = i/200; int k = i - r*200;
    int p = p0+r;
    hrow[r][k] = (k<100) ? hseq[(long)p*100+k] : hseq[((long)NWORDS + p)*100 + (k-100)];
  }
  __syncthreads();
  int r = tid>>5; int c = tid&31;
  if (c<25){
    float a0=0.f,a1=0.f,a2=0.f,a3=0.f;
    #pragma unroll 10
    for (int k=0;k<200;k+=4){
      float4 h4 = *(const float4*)&hrow[r][k];
      float4 w4 = *(const float4*)&WsT[c][k];
      a0 += h4.x*w4.x; a1 += h4.y*w4.y;
      a2 += h4.z*w4.z; a3 += h4.w*w4.w;
    }
    em[(long)(p0+r)*25 + c] = btag[c] + (a0+a1)+(a2+a3);
  }
}

// ---------------- Kernel 6: CRF per sequence (R17: 1 exp/step via etr precompute).
__global__ __launch_bounds__(64) void k_crf(const float* __restrict__ em,
    const int* __restrict__ tag, const float* __restrict__ trans,
    const float* __restrict__ start, const float* __restrict__ endv,
    float* __restrict__ part){
  int s = blockIdx.x;
  int lane = threadIdx.x;
  const float* emb = em + (long)s*256*25;
  float etr[25];
  #pragma unroll
  for (int k=0;k<25;k++) etr[k] = (lane<25) ? __expf(trans[k*25+lane]) : 0.f;
  float alpha = (lane<25) ? (start[lane] + emb[lane]) : 0.f;
  float enext = (lane<25) ? emb[25+lane] : 0.f;
  for (int t=1;t<256;t++){
    float ecur = enext;
    if (t<255 && lane<25) enext = emb[(t+1)*25 + lane];
    float base = RL(alpha, 0);
    float e = __expf(alpha - base);
    float s0=0.f,s1=0.f,s2=0.f,s3=0.f,s4=0.f;
    #pragma unroll
    for (int k=0;k<5;k++) s0 += RL(e,k)    * etr[k];
    #pragma unroll
    for (int k=0;k<5;k++) s1 += RL(e,5+k)  * etr[5+k];
    #pragma unroll
    for (int k=0;k<5;k++) s2 += RL(e,10+k) * etr[10+k];
    #pragma unroll
    for (int k=0;k<5;k++) s3 += RL(e,15+k) * etr[15+k];
    #pragma unroll
    for (int k=0;k<5;k++) s4 += RL(e,20+k) * etr[20+k];
    float ssum = ((s0+s1)+(s2+s3))+s4;
    alpha = __logf(ssum) + base + ecur;
  }
  float val = (lane<25) ? (alpha + endv[lane]) : -1e30f;
  float m2 = -1e30f;
  #pragma unroll
  for (int k=0;k<25;k++) m2 = fmaxf(m2, RL(val,k));
  float s2s = 0.f;
  #pragma unroll
  for (int k=0;k<25;k++) s2s += __expf(RL(val,k) - m2);
  float logZ = __logf(s2s) + m2;
  const int* tg = tag + s*256;
  float gp = 0.f;
  for (int t=lane; t<256; t+=64){
    int a = tg[t];
    gp += emb[t*25 + a];
    if (t<255) gp += trans[a*25 + tg[t+1]];
  }
  #pragma unroll
  for (int off=32; off; off>>=1) gp += __shfl_xor(gp, off, 64);
  if (lane==0){
    float gold = gp + start[tg[0]] + endv[tg[255]];
    part[s] = logZ - gold;
  }
}

// ---------------- Kernel 7: final reduce
__global__ __launch_bounds__(64) void k_red(const float* __restrict__ part, float* __restrict__ out){
  float v = part[threadIdx.x];
  #pragma unroll
  for (int off=32; off; off>>=1) v += __shfl_xor(v, off, 64);
  if (threadIdx.x==0) out[0] = v;
}

extern "C" void kernel_launch(void* const* d_in, const int* in_sizes, int n_in,
                              void* d_out, int out_size, void* d_ws, size_t ws_size,
                              hipStream_t stream){
  const int* tok          = (const int*)d_in[0];
  const int* tagp         = (const int*)d_in[1];
  const int* char_tensor  = (const int*)d_in[3];
  const int* char_lengths = (const int*)d_in[4];
  const int* recover      = (const int*)d_in[5];
  const float* word_emb = (const float*)d_in[6];
  const float* char_emb = (const float*)d_in[7];
  const float* cWih_f=(const float*)d_in[8];  const float* cWhh_f=(const float*)d_in[9];  const float* cb_f=(const float*)d_in[10];
  const float* cWih_b=(const float*)d_in[11]; const float* cWhh_b=(const float*)d_in[12]; const float* cb_b=(const float*)d_in[13];
  const float* wWih_f=(const float*)d_in[14]; const float* wWhh_f=(const float*)d_in[15]; const float* wb_f=(const float*)d_in[16];
  const float* wWih_b=(const float*)d_in[17]; const float* wWhh_b=(const float*)d_in[18]; const float* wb_b=(const float*)d_in[19];
  const float* W_tag=(const float*)d_in[20];  const float* b_tag=(const float*)d_in[21];
  const float* trans=(const float*)d_in[22];  const float* startv=(const float*)d_in[23]; const float* endv=(const float*)d_in[24];

  float* ws  = (float*)d_ws;
  float* gxc = ws;                 // [0, 25600)
  float* cf  = ws + 25600;         // [25600, 943104)
  float* gx  = ws + 943104;        // [943104, 14050304)
  float* hseq= ws + 14050304;      // [14050304, 17327104)
  float* em  = ws;                 // overlays gxc+cf (dead after k_wih), 409600
  float* part= ws + 17327104;      // 64
  int*   meta= (int*)(ws + 17327168);  // hist[16]+cursor[16]+pad
  int*   widx= meta + 64;              // 16384 ints (high water ~69.4 MB)
  float* out = (float*)d_out;

  k_zero   <<<1,   64,  0, stream>>>(meta);
  k_gxc    <<<100, 256, 0, stream>>>(char_emb, cWih_f, cb_f, cWih_b, cb_b, gxc);
  k_hist   <<<64,  256, 0, stream>>>(char_lengths, meta);
  k_scan   <<<1,   64,  0, stream>>>(meta, meta+16);
  k_scatter<<<64,  256, 0, stream>>>(char_lengths, meta+16, widx);
  k_char   <<<6554,512, 0, stream>>>(char_tensor, char_lengths, widx, cWhh_f, cWhh_b, gxc, cf);
  k_wih    <<<1024,256, 0, stream>>>(tok, recover, word_emb, cf, wWih_f, wb_f, wWih_b, wb_b, gx);
  k_wlstm  <<<128, 448, 0, stream>>>(gx, wWhh_f, wWhh_b, hseq);
  k_em     <<<2048,256, 0, stream>>>(hseq, W_tag, b_tag, em);
  k_crf    <<<64,  64,  0, stream>>>(em, tagp, trans, startv, endv, part);
  k_red    <<<1,   64,  0, stream>>>(part, out);
}